// Round 2
// baseline (601.535 us; speedup 1.0000x reference)
//
#include <hip/hip_runtime.h>
#include <math.h>

#define NN 50000
#define NE 800000
#define KD 128
#define TT 4
#define SLOPE 0.22916666666666666f  /* 11/48, torch RReLU eval negative slope */

// ---------------------------------------------------------------------------
// Evolve kernel: W_e = GRU^4(W0). Column-separable: block = (layer, column j).
// 128 threads; thread i owns Q[i][j]. Gate matrices staged 64KB at a time in
// LDS with chunk rotation ((c+row)&31) so ds_read_b128 rows hit distinct banks.
// ---------------------------------------------------------------------------
__device__ __forceinline__ void stage_mat(const float4* __restrict__ M4, float4* sM4, int tid){
#pragma unroll
  for (int s = 0; s < 32; ++s){
    int g4 = tid + 128*s;          // 4096 float4 chunks, coalesced
    int rr = g4 >> 5, c = g4 & 31;
    sM4[rr*32 + ((c + rr) & 31)] = M4[g4];
  }
}

__device__ __forceinline__ float dot_row(const float4* sM4, const float* svec, int i){
  const float4* v4 = (const float4*)svec;
  float acc = 0.f;
#pragma unroll
  for (int c = 0; c < 32; ++c){
    float4 m  = sM4[i*32 + ((c + i) & 31)];
    float4 qv = v4[c];                       // broadcast (same addr all lanes)
    acc = fmaf(m.x, qv.x, acc); acc = fmaf(m.y, qv.y, acc);
    acc = fmaf(m.z, qv.z, acc); acc = fmaf(m.w, qv.w, acc);
  }
  return acc;
}

__global__ __launch_bounds__(128) void evolve_kernel(
    const float* __restrict__ Wa, const float* __restrict__ gWa, const float* __restrict__ gUa, const float* __restrict__ gba,
    const float* __restrict__ Wb, const float* __restrict__ gWb, const float* __restrict__ gUb, const float* __restrict__ gbb,
    float* __restrict__ WeA, float* __restrict__ WeB)
{
  __shared__ float4 sM4[128*32];
  __shared__ __align__(16) float s_q[128];
  __shared__ __align__(16) float s_rq[128];
  const int layer = blockIdx.x >> 7;
  const int j = blockIdx.x & 127;
  const int i = threadIdx.x;
  const float* W0 = layer ? Wb  : Wa;
  const float* gW = layer ? gWb : gWa;
  const float* gU = layer ? gUb : gUa;
  const float* gb = layer ? gbb : gba;
  float* We = layer ? WeB : WeA;

  float q = W0[i*KD + j];
  const float b0 = gb[0*KD*KD + i*KD + j];
  const float b1 = gb[1*KD*KD + i*KD + j];
  const float b2 = gb[2*KD*KD + i*KD + j];
  const float4* gW4 = (const float4*)gW;
  const float4* gU4 = (const float4*)gU;
  const int MC = KD*KD/4;  // float4 per 128x128 matrix

  for (int it = 0; it < TT; ++it){
    __syncthreads();                 // prior iter's readers done
    s_q[i] = q;
    stage_mat(gW4 + 0*MC, sM4, i);
    __syncthreads();
    float t0 = b0 + dot_row(sM4, s_q, i);
    __syncthreads();
    stage_mat(gU4 + 0*MC, sM4, i);
    __syncthreads();
    t0 += dot_row(sM4, s_q, i);
    __syncthreads();
    stage_mat(gW4 + 1*MC, sM4, i);
    __syncthreads();
    float t1 = b1 + dot_row(sM4, s_q, i);
    __syncthreads();
    stage_mat(gU4 + 1*MC, sM4, i);
    __syncthreads();
    t1 += dot_row(sM4, s_q, i);
    __syncthreads();
    stage_mat(gW4 + 2*MC, sM4, i);
    __syncthreads();
    float t2 = b2 + dot_row(sM4, s_q, i);
    float z = 1.f/(1.f + expf(-t0));
    float r = 1.f/(1.f + expf(-t1));
    __syncthreads();                 // dot readers of sM4/s_q done
    s_rq[i] = r*q;
    stage_mat(gU4 + 2*MC, sM4, i);
    __syncthreads();
    t2 += dot_row(sM4, s_rq, i);
    float h = tanhf(t2);
    q = (1.f - z)*q + z*h;
  }
  We[i*KD + j] = q;
}

// ---------------------------------------------------------------------------
// GEMM: Y[nrows x 128] = X[nrows x 128] @ W[128 x 128], fp32 vector ALU.
// 512 threads, 128-row tile. Thread = (rg,cg): 4 rows x 8 cols micro-tile.
// W staged with bit-permuted chunk slots so the per-k float4 reads land in
// distinct bank quads; X staged with row stride 132 floats (16B aligned pad).
// ---------------------------------------------------------------------------
__device__ __forceinline__ int wperm(int c){
  return ((c >> 1) & 7) | ((c & 1) << 3) | ((c >> 4) << 4);
}

__global__ __launch_bounds__(512) void gemm_kernel(
    const float* __restrict__ X, const float* __restrict__ W,
    float* __restrict__ Y, int nrows)
{
  __shared__ float4 sX4[128*33];   // row stride 33 chunks = 132 floats
  __shared__ float4 sW4[128*32];
  const int tid = threadIdx.x;
  const int rg = tid >> 4;         // 0..31 -> rows rg*4..rg*4+3
  const int cg = tid & 15;         // 0..15 -> cols cg*8..cg*8+7
  const int rbase = blockIdx.x * 128;

  const float4* X4 = (const float4*)X;
  const float4* W4 = (const float4*)W;
#pragma unroll
  for (int s = 0; s < 8; ++s){
    int g4 = tid + 512*s;          // 4096 chunks of X tile
    int r = g4 >> 5, c = g4 & 31;
    float4 v = make_float4(0.f,0.f,0.f,0.f);
    int row = rbase + r;
    if (row < nrows) v = X4[(size_t)row*32 + c];
    sX4[r*33 + c] = v;
  }
#pragma unroll
  for (int s = 0; s < 8; ++s){
    int g4 = tid + 512*s;          // 4096 chunks of W (128 rows x 32 chunks)
    int k = g4 >> 5, c = g4 & 31;
    sW4[k*32 + wperm(c)] = W4[g4];
  }
  __syncthreads();

  const float* sXf = (const float*)sX4;            // stride 132 floats
  const int slotA = (cg & 7) | ((cg >> 3) << 4);   // = wperm(2*cg)
  const int slotB = slotA | 8;                     // = wperm(2*cg+1)
  float acc[4][8];
#pragma unroll
  for (int a = 0; a < 4; ++a)
#pragma unroll
    for (int b = 0; b < 8; ++b) acc[a][b] = 0.f;

#pragma unroll 8
  for (int k = 0; k < 128; ++k){
    float4 wa = sW4[k*32 + slotA];
    float4 wb = sW4[k*32 + slotB];
#pragma unroll
    for (int rr = 0; rr < 4; ++rr){
      float xv = sXf[(rg*4 + rr)*132 + k];
      acc[rr][0] = fmaf(xv, wa.x, acc[rr][0]);
      acc[rr][1] = fmaf(xv, wa.y, acc[rr][1]);
      acc[rr][2] = fmaf(xv, wa.z, acc[rr][2]);
      acc[rr][3] = fmaf(xv, wa.w, acc[rr][3]);
      acc[rr][4] = fmaf(xv, wb.x, acc[rr][4]);
      acc[rr][5] = fmaf(xv, wb.y, acc[rr][5]);
      acc[rr][6] = fmaf(xv, wb.z, acc[rr][6]);
      acc[rr][7] = fmaf(xv, wb.w, acc[rr][7]);
    }
  }

  float4* Y4 = (float4*)Y;
#pragma unroll
  for (int rr = 0; rr < 4; ++rr){
    int row = rbase + rg*4 + rr;
    if (row < nrows){
      Y4[(size_t)row*32 + cg*2 + 0] = make_float4(acc[rr][0],acc[rr][1],acc[rr][2],acc[rr][3]);
      Y4[(size_t)row*32 + cg*2 + 1] = make_float4(acc[rr][4],acc[rr][5],acc[rr][6],acc[rr][7]);
    }
  }
}

// ---------------------------------------------------------------------------
// Edge binning: histogram -> exclusive scan -> scatter into row-sorted order.
// ---------------------------------------------------------------------------
__global__ __launch_bounds__(256) void hist_kernel(const int* __restrict__ row, int* __restrict__ counts){
  int idx = blockIdx.x*blockDim.x + threadIdx.x;
  int stride = gridDim.x*blockDim.x;
  for (int e = idx; e < NE; e += stride) atomicAdd(&counts[row[e]], 1);
}

__global__ __launch_bounds__(1024) void scan_kernel(const int* __restrict__ counts,
                                                    int* __restrict__ starts, int* __restrict__ cursors){
  __shared__ int sb[1024];
  const int CH = (NN + 1023) / 1024;  // 49
  int t = threadIdx.x;
  int base = t * CH;
  int local = 0;
  for (int u = 0; u < CH; ++u){ int idx = base + u; if (idx < NN) local += counts[idx]; }
  sb[t] = local;
  __syncthreads();
  for (int off = 1; off < 1024; off <<= 1){
    int v = sb[t];
    int add = (t >= off) ? sb[t - off] : 0;
    __syncthreads();
    sb[t] = v + add;
    __syncthreads();
  }
  int run = (t == 0) ? 0 : sb[t-1];
  for (int u = 0; u < CH; ++u){
    int idx = base + u;
    if (idx < NN){ starts[idx] = run; cursors[idx] = run; run += counts[idx]; }
  }
  if (t == 1023) starts[NN] = run;
}

__global__ __launch_bounds__(256) void scatter_kernel(const int* __restrict__ row, const int* __restrict__ col,
                                                      const float* __restrict__ val, int* __restrict__ cursors,
                                                      int* __restrict__ sCol, float* __restrict__ sVal){
  int idx = blockIdx.x*blockDim.x + threadIdx.x;
  int stride = gridDim.x*blockDim.x;
  for (int e = idx; e < NE; e += stride){
    int r = row[e];
    int p = atomicAdd(&cursors[r], 1);
    sCol[p] = col[e];
    sVal[p] = val[e];
  }
}

// ---------------------------------------------------------------------------
// SpMM: one 128-thread block per output row; thread j owns column j.
// Per edge: coalesced 512B row gather of Y[col], register accumulate. rrelu
// fused into the writeback.
// ---------------------------------------------------------------------------
__global__ __launch_bounds__(128) void spmm_kernel(const int* __restrict__ starts, const int* __restrict__ sCol,
                                                   const float* __restrict__ sVal, const float* __restrict__ Y,
                                                   float* __restrict__ out){
  int r = blockIdx.x;
  int j = threadIdx.x;
  int e0 = starts[r], e1 = starts[r+1];
  float acc = 0.f;
  for (int e = e0; e < e1; ++e){
    int c = sCol[e];
    float v = sVal[e];
    acc = fmaf(v, Y[(size_t)c*KD + j], acc);
  }
  out[(size_t)r*KD + j] = (acc >= 0.f) ? acc : acc * SLOPE;
}

// ---------------------------------------------------------------------------
extern "C" void kernel_launch(void* const* d_in, const int* in_sizes, int n_in,
                              void* d_out, int out_size, void* d_ws, size_t ws_size,
                              hipStream_t stream)
{
  const float* features = (const float*)d_in[0];
  const int*   adj_row  = (const int*)d_in[1];
  const int*   adj_col  = (const int*)d_in[2];
  const float* adj_val  = (const float*)d_in[3];
  const float* W1  = (const float*)d_in[4];
  const float* g1W = (const float*)d_in[5];
  const float* g1U = (const float*)d_in[6];
  const float* g1b = (const float*)d_in[7];
  const float* W2  = (const float*)d_in[8];
  const float* g2W = (const float*)d_in[9];
  const float* g2U = (const float*)d_in[10];
  const float* g2b = (const float*)d_in[11];

  // only timestep T-1 ever reaches the output
  const float* feat3 = features + (size_t)(TT-1)*NN*KD;
  const int*   row3  = adj_row + (size_t)(TT-1)*NE;
  const int*   col3  = adj_col + (size_t)(TT-1)*NE;
  const float* val3  = adj_val + (size_t)(TT-1)*NE;

  float* ws   = (float*)d_ws;
  float* W1e  = ws;                       // 16384 f
  float* W2e  = W1e + 16384;              // 16384 f
  int* counts  = (int*)(W2e + 16384);     // 50000 (padded 50016)
  int* starts  = counts + 50016;          // 50001 (padded 50016)
  int* cursors = starts + 50016;          // 50000 (padded 50016)
  int* sCol    = cursors + 50016;         // 800000
  float* sVal  = (float*)(sCol + NE);     // 800000
  float* XW    = sVal + NE;               // 6,400,000 (25.6 MB)
  float* outF  = (float*)d_out;           // doubles as h1 scratch

  hipMemsetAsync(counts, 0, NN*sizeof(int), stream);
  evolve_kernel<<<256, 128, 0, stream>>>(W1,g1W,g1U,g1b, W2,g2W,g2U,g2b, W1e, W2e);
  hist_kernel<<<1024, 256, 0, stream>>>(row3, counts);
  scan_kernel<<<1, 1024, 0, stream>>>(counts, starts, cursors);
  scatter_kernel<<<1024, 256, 0, stream>>>(row3, col3, val3, cursors, sCol, sVal);

  gemm_kernel<<<(NN + 127)/128, 512, 0, stream>>>(feat3, W1e, XW, NN);   // X3 @ W1e
  spmm_kernel<<<NN, 128, 0, stream>>>(starts, sCol, sVal, XW, outF);     // h1 -> d_out
  gemm_kernel<<<(NN + 127)/128, 512, 0, stream>>>(outF, W2e, XW, NN);    // h1 @ W2e
  spmm_kernel<<<NN, 128, 0, stream>>>(starts, sCol, sVal, XW, outF);     // final -> d_out
}

// Round 3
// 549.611 us; speedup vs baseline: 1.0945x; 1.0945x over previous
//
#include <hip/hip_runtime.h>
#include <math.h>

#define NN 50000
#define NE 800000
#define KD 128
#define SLOPE 0.22916666666666666f  /* 11/48, torch RReLU eval negative slope */

__device__ __forceinline__ void fma4(float s, const float4& q, float4& acc){
  acc.x = fmaf(s, q.x, acc.x); acc.y = fmaf(s, q.y, acc.y);
  acc.z = fmaf(s, q.z, acc.z); acc.w = fmaf(s, q.w, acc.w);
}

// ---------------------------------------------------------------------------
// Evolve, kernel A: T[layer][g] = Mg @ Q, Mg = gW[g] + (g<2 ? gU[g] : 0).
// Grid: 24 blocks = layer(2) x {gate(3) x rowhalf(2)} x colhalf(2).
// 256 thr, 64x64 tile, 4x4 micro-tile, K=128 single pass.
// ---------------------------------------------------------------------------
__global__ __launch_bounds__(256) void evolveA_kernel(
    const float* __restrict__ gW_0, const float* __restrict__ gU_0,
    const float* __restrict__ gW_1, const float* __restrict__ gU_1,
    const float* __restrict__ Q_0, const float* __restrict__ Q_1,
    float* __restrict__ T)   // [2][3][128][128]
{
  __shared__ float4 sA[64*33];   // A-tile rows padded to 132 floats
  __shared__ float4 sQ[128*16];  // Q-tile [128][64]
  const int bx = blockIdx.x;
  const int layer = bx / 12;
  const int rt = (bx % 12) >> 1;
  const int ct = bx & 1;
  const int gate = rt >> 1;
  const int rbase = (rt & 1) * 64;
  const int tid = threadIdx.x;
  const float4* gW4 = (const float4*)(layer ? gW_1 : gW_0);
  const float4* gU4 = (const float4*)(layer ? gU_1 : gU_0);
  const float4* Q4  = (const float4*)(layer ? Q_1  : Q_0);

#pragma unroll
  for (int s = 0; s < 8; ++s){
    int ch = tid + 256*s;                    // 2048 chunks: 64 rows x 32
    int r = ch >> 5, c = ch & 31;
    int goff = gate*4096 + (rbase + r)*32 + c;
    float4 a = gW4[goff];
    if (gate < 2){ float4 u = gU4[goff]; a.x+=u.x; a.y+=u.y; a.z+=u.z; a.w+=u.w; }
    sA[r*33 + c] = a;
  }
#pragma unroll
  for (int s = 0; s < 8; ++s){
    int ch = tid + 256*s;                    // 2048 chunks: 128 rows x 16
    int kr = ch >> 4, qc = ch & 15;
    sQ[kr*16 + qc] = Q4[kr*32 + ct*16 + qc];
  }
  __syncthreads();

  const int it = tid & 15, jt = tid >> 4;
  float4 acc[4];
  acc[0]=acc[1]=acc[2]=acc[3]=make_float4(0.f,0.f,0.f,0.f);
  const float* sAf = (const float*)sA;
#pragma unroll 4
  for (int kq = 0; kq < 32; ++kq){
    float4 q0 = sQ[(kq*4+0)*16 + jt];
    float4 q1 = sQ[(kq*4+1)*16 + jt];
    float4 q2 = sQ[(kq*4+2)*16 + jt];
    float4 q3 = sQ[(kq*4+3)*16 + jt];
#pragma unroll
    for (int r = 0; r < 4; ++r){
      float4 a = *(const float4*)(sAf + (it*4+r)*132 + kq*4);
      fma4(a.x, q0, acc[r]); fma4(a.y, q1, acc[r]);
      fma4(a.z, q2, acc[r]); fma4(a.w, q3, acc[r]);
    }
  }
  float4* T4 = (float4*)T;
  const int tb = (layer*3 + gate)*4096;
#pragma unroll
  for (int r = 0; r < 4; ++r){
    int row = rbase + it*4 + r;
    T4[tb + row*32 + ct*16 + jt] = acc[r];
  }
}

// ---------------------------------------------------------------------------
// Evolve, kernel B: H = gU[2] @ (sigmoid(T1+b1) * Q); epilogue does
// z = sigmoid(T0+b0), h = tanh(T2+b2+H), Qd = (1-z)Q + z h. Grid: 8 blocks.
// ---------------------------------------------------------------------------
__global__ __launch_bounds__(256) void evolveB_kernel(
    const float* __restrict__ gU_0, const float* __restrict__ gU_1,
    const float* __restrict__ gb_0, const float* __restrict__ gb_1,
    const float* __restrict__ T,
    const float* __restrict__ Q_0, const float* __restrict__ Q_1,
    float* __restrict__ Qd_0, float* __restrict__ Qd_1)
{
  __shared__ float4 sA[64*33];
  __shared__ float4 sQ[128*16];
  const int bx = blockIdx.x;
  const int layer = bx >> 2;
  const int rt = (bx >> 1) & 1;
  const int ct = bx & 1;
  const int rbase = rt * 64;
  const int tid = threadIdx.x;
  const float4* gU4 = (const float4*)(layer ? gU_1 : gU_0);
  const float4* gb4 = (const float4*)(layer ? gb_1 : gb_0);
  const float4* Q4  = (const float4*)(layer ? Q_1  : Q_0);
  const float4* T4  = (const float4*)T;
  float4* Qd4 = (float4*)(layer ? Qd_1 : Qd_0);

#pragma unroll
  for (int s = 0; s < 8; ++s){
    int ch = tid + 256*s;
    int r = ch >> 5, c = ch & 31;
    sA[r*33 + c] = gU4[2*4096 + (rbase + r)*32 + c];
  }
#pragma unroll
  for (int s = 0; s < 8; ++s){
    int ch = tid + 256*s;
    int kr = ch >> 4, qc = ch & 15;
    int fo = kr*32 + ct*16 + qc;
    float4 t1 = T4[(layer*3+1)*4096 + fo];
    float4 b1 = gb4[1*4096 + fo];
    float4 q  = Q4[fo];
    float4 rq;
    rq.x = q.x / (1.f + expf(-(t1.x + b1.x)));
    rq.y = q.y / (1.f + expf(-(t1.y + b1.y)));
    rq.z = q.z / (1.f + expf(-(t1.z + b1.z)));
    rq.w = q.w / (1.f + expf(-(t1.w + b1.w)));
    sQ[kr*16 + qc] = rq;
  }
  __syncthreads();

  const int it = tid & 15, jt = tid >> 4;
  float4 acc[4];
  acc[0]=acc[1]=acc[2]=acc[3]=make_float4(0.f,0.f,0.f,0.f);
  const float* sAf = (const float*)sA;
#pragma unroll 4
  for (int kq = 0; kq < 32; ++kq){
    float4 q0 = sQ[(kq*4+0)*16 + jt];
    float4 q1 = sQ[(kq*4+1)*16 + jt];
    float4 q2 = sQ[(kq*4+2)*16 + jt];
    float4 q3 = sQ[(kq*4+3)*16 + jt];
#pragma unroll
    for (int r = 0; r < 4; ++r){
      float4 a = *(const float4*)(sAf + (it*4+r)*132 + kq*4);
      fma4(a.x, q0, acc[r]); fma4(a.y, q1, acc[r]);
      fma4(a.z, q2, acc[r]); fma4(a.w, q3, acc[r]);
    }
  }
#pragma unroll
  for (int r = 0; r < 4; ++r){
    int row = rbase + it*4 + r;
    int fo = row*32 + ct*16 + jt;
    float4 t0 = T4[(layer*3+0)*4096 + fo];
    float4 b0 = gb4[0*4096 + fo];
    float4 t2 = T4[(layer*3+2)*4096 + fo];
    float4 b2 = gb4[2*4096 + fo];
    float4 q  = Q4[fo];
    float4 o;
    { float z = 1.f/(1.f + expf(-(t0.x + b0.x)));
      float h = tanhf(t2.x + b2.x + acc[r].x);
      o.x = (1.f - z)*q.x + z*h; }
    { float z = 1.f/(1.f + expf(-(t0.y + b0.y)));
      float h = tanhf(t2.y + b2.y + acc[r].y);
      o.y = (1.f - z)*q.y + z*h; }
    { float z = 1.f/(1.f + expf(-(t0.z + b0.z)));
      float h = tanhf(t2.z + b2.z + acc[r].z);
      o.z = (1.f - z)*q.z + z*h; }
    { float z = 1.f/(1.f + expf(-(t0.w + b0.w)));
      float h = tanhf(t2.w + b2.w + acc[r].w);
      o.w = (1.f - z)*q.w + z*h; }
    Qd4[fo] = o;
  }
}

// ---------------------------------------------------------------------------
// GEMM: Y[nrows x 128] = X[nrows x 128] @ W[128 x 128], fp32 vector ALU.
// ---------------------------------------------------------------------------
__device__ __forceinline__ int wperm(int c){
  return ((c >> 1) & 7) | ((c & 1) << 3) | ((c >> 4) << 4);
}

__global__ __launch_bounds__(512) void gemm_kernel(
    const float* __restrict__ X, const float* __restrict__ W,
    float* __restrict__ Y, int nrows)
{
  __shared__ float4 sX4[128*33];   // row stride 132 floats
  __shared__ float4 sW4[128*32];
  const int tid = threadIdx.x;
  const int rg = tid >> 4;
  const int cg = tid & 15;
  const int rbase = blockIdx.x * 128;

  const float4* X4 = (const float4*)X;
  const float4* W4 = (const float4*)W;
#pragma unroll
  for (int s = 0; s < 8; ++s){
    int g4 = tid + 512*s;
    int r = g4 >> 5, c = g4 & 31;
    float4 v = make_float4(0.f,0.f,0.f,0.f);
    int row = rbase + r;
    if (row < nrows) v = X4[(size_t)row*32 + c];
    sX4[r*33 + c] = v;
  }
#pragma unroll
  for (int s = 0; s < 8; ++s){
    int g4 = tid + 512*s;
    int k = g4 >> 5, c = g4 & 31;
    sW4[k*32 + wperm(c)] = W4[g4];
  }
  __syncthreads();

  const float* sXf = (const float*)sX4;
  const int slotA = (cg & 7) | ((cg >> 3) << 4);
  const int slotB = slotA | 8;
  float acc[4][8];
#pragma unroll
  for (int a = 0; a < 4; ++a)
#pragma unroll
    for (int b = 0; b < 8; ++b) acc[a][b] = 0.f;

#pragma unroll 8
  for (int k = 0; k < 128; ++k){
    float4 wa = sW4[k*32 + slotA];
    float4 wb = sW4[k*32 + slotB];
#pragma unroll
    for (int rr = 0; rr < 4; ++rr){
      float xv = sXf[(rg*4 + rr)*132 + k];
      acc[rr][0] = fmaf(xv, wa.x, acc[rr][0]);
      acc[rr][1] = fmaf(xv, wa.y, acc[rr][1]);
      acc[rr][2] = fmaf(xv, wa.z, acc[rr][2]);
      acc[rr][3] = fmaf(xv, wa.w, acc[rr][3]);
      acc[rr][4] = fmaf(xv, wb.x, acc[rr][4]);
      acc[rr][5] = fmaf(xv, wb.y, acc[rr][5]);
      acc[rr][6] = fmaf(xv, wb.z, acc[rr][6]);
      acc[rr][7] = fmaf(xv, wb.w, acc[rr][7]);
    }
  }

  float4* Y4 = (float4*)Y;
#pragma unroll
  for (int rr = 0; rr < 4; ++rr){
    int row = rbase + rg*4 + rr;
    if (row < nrows){
      Y4[(size_t)row*32 + cg*2 + 0] = make_float4(acc[rr][0],acc[rr][1],acc[rr][2],acc[rr][3]);
      Y4[(size_t)row*32 + cg*2 + 1] = make_float4(acc[rr][4],acc[rr][5],acc[rr][6],acc[rr][7]);
    }
  }
}

// ---------------------------------------------------------------------------
// Edge binning: histogram -> exclusive scan -> scatter into row-sorted order.
// ---------------------------------------------------------------------------
__global__ __launch_bounds__(256) void hist_kernel(const int* __restrict__ row, int* __restrict__ counts){
  int idx = blockIdx.x*blockDim.x + threadIdx.x;
  int stride = gridDim.x*blockDim.x;
  for (int e = idx; e < NE; e += stride) atomicAdd(&counts[row[e]], 1);
}

__global__ __launch_bounds__(1024) void scan_kernel(const int* __restrict__ counts,
                                                    int* __restrict__ starts, int* __restrict__ cursors){
  __shared__ int sb[1024];
  const int CH = (NN + 1023) / 1024;  // 49
  int t = threadIdx.x;
  int base = t * CH;
  int local = 0;
  for (int u = 0; u < CH; ++u){ int idx = base + u; if (idx < NN) local += counts[idx]; }
  sb[t] = local;
  __syncthreads();
  for (int off = 1; off < 1024; off <<= 1){
    int v = sb[t];
    int add = (t >= off) ? sb[t - off] : 0;
    __syncthreads();
    sb[t] = v + add;
    __syncthreads();
  }
  int run = (t == 0) ? 0 : sb[t-1];
  for (int u = 0; u < CH; ++u){
    int idx = base + u;
    if (idx < NN){ starts[idx] = run; cursors[idx] = run; run += counts[idx]; }
  }
  if (t == 1023) starts[NN] = run;
}

__global__ __launch_bounds__(256) void scatter_kernel(const int* __restrict__ row, const int* __restrict__ col,
                                                      const float* __restrict__ val, int* __restrict__ cursors,
                                                      int* __restrict__ sCol, float* __restrict__ sVal){
  int idx = blockIdx.x*blockDim.x + threadIdx.x;
  int stride = gridDim.x*blockDim.x;
  for (int e = idx; e < NE; e += stride){
    int r = row[e];
    int p = atomicAdd(&cursors[r], 1);
    sCol[p] = col[e];
    sVal[p] = val[e];
  }
}

// ---------------------------------------------------------------------------
// SpMM: one 128-thread block per output row; thread j owns column j.
// ---------------------------------------------------------------------------
__global__ __launch_bounds__(128) void spmm_kernel(const int* __restrict__ starts, const int* __restrict__ sCol,
                                                   const float* __restrict__ sVal, const float* __restrict__ Y,
                                                   float* __restrict__ out){
  int r = blockIdx.x;
  int j = threadIdx.x;
  int e0 = starts[r], e1 = starts[r+1];
  float acc = 0.f;
  for (int e = e0; e < e1; ++e){
    int c = sCol[e];
    float v = sVal[e];
    acc = fmaf(v, Y[(size_t)c*KD + j], acc);
  }
  out[(size_t)r*KD + j] = (acc >= 0.f) ? acc : acc * SLOPE;
}

// ---------------------------------------------------------------------------
extern "C" void kernel_launch(void* const* d_in, const int* in_sizes, int n_in,
                              void* d_out, int out_size, void* d_ws, size_t ws_size,
                              hipStream_t stream)
{
  const float* features = (const float*)d_in[0];
  const int*   adj_row  = (const int*)d_in[1];
  const int*   adj_col  = (const int*)d_in[2];
  const float* adj_val  = (const float*)d_in[3];
  const float* W1  = (const float*)d_in[4];
  const float* g1W = (const float*)d_in[5];
  const float* g1U = (const float*)d_in[6];
  const float* g1b = (const float*)d_in[7];
  const float* W2  = (const float*)d_in[8];
  const float* g2W = (const float*)d_in[9];
  const float* g2U = (const float*)d_in[10];
  const float* g2b = (const float*)d_in[11];

  // only timestep T-1 ever reaches the output
  const float* feat3 = features + (size_t)3*NN*KD;
  const int*   row3  = adj_row + (size_t)3*NE;
  const int*   col3  = adj_col + (size_t)3*NE;
  const float* val3  = adj_val + (size_t)3*NE;

  float* ws    = (float*)d_ws;
  float* QP    = ws;                      // ping-pong Q: [2 bufs][2 layers][16384]
  float* Tbuf  = QP + 65536;              // [2][3][16384] = 98304
  int* counts  = (int*)(Tbuf + 98304);    // 50000 (padded 50016)
  int* starts  = counts + 50016;
  int* cursors = starts + 50016;
  int* sCol    = cursors + 50016;         // 800000
  float* sVal  = (float*)(sCol + NE);     // 800000
  float* XW    = sVal + NE;               // 6,400,000 (25.6 MB)
  float* outF  = (float*)d_out;

  float* QA0 = QP;           float* QA1 = QP + 16384;   // buffer A (layers 0,1)
  float* QB0 = QP + 32768;   float* QB1 = QP + 49152;   // buffer B

  hipMemsetAsync(counts, 0, NN*sizeof(int), stream);
  hist_kernel<<<1024, 256, 0, stream>>>(row3, counts);
  scan_kernel<<<1, 1024, 0, stream>>>(counts, starts, cursors);
  scatter_kernel<<<1024, 256, 0, stream>>>(row3, col3, val3, cursors, sCol, sVal);

  // GRU^4 on both layers' weights: iter0 reads W1/W2, then ping-pong A<->B.
  evolveA_kernel<<<24, 256, 0, stream>>>(g1W,g1U,g2W,g2U, W1,  W2,  Tbuf);
  evolveB_kernel<<< 8, 256, 0, stream>>>(g1U,g2U,g1b,g2b, Tbuf, W1,  W2,  QA0, QA1);
  evolveA_kernel<<<24, 256, 0, stream>>>(g1W,g1U,g2W,g2U, QA0, QA1, Tbuf);
  evolveB_kernel<<< 8, 256, 0, stream>>>(g1U,g2U,g1b,g2b, Tbuf, QA0, QA1, QB0, QB1);
  evolveA_kernel<<<24, 256, 0, stream>>>(g1W,g1U,g2W,g2U, QB0, QB1, Tbuf);
  evolveB_kernel<<< 8, 256, 0, stream>>>(g1U,g2U,g1b,g2b, Tbuf, QB0, QB1, QA0, QA1);
  evolveA_kernel<<<24, 256, 0, stream>>>(g1W,g1U,g2W,g2U, QA0, QA1, Tbuf);
  evolveB_kernel<<< 8, 256, 0, stream>>>(g1U,g2U,g1b,g2b, Tbuf, QA0, QA1, QB0, QB1);
  // evolved weights: W1e = QB0, W2e = QB1

  gemm_kernel<<<(NN + 127)/128, 512, 0, stream>>>(feat3, QB0, XW, NN);   // X3 @ W1e
  spmm_kernel<<<NN, 128, 0, stream>>>(starts, sCol, sVal, XW, outF);     // h1 -> d_out
  gemm_kernel<<<(NN + 127)/128, 512, 0, stream>>>(outF, QB1, XW, NN);    // h1 @ W2e
  spmm_kernel<<<NN, 128, 0, stream>>>(starts, sCol, sVal, XW, outF);     // final -> d_out
}

// Round 4
// 431.394 us; speedup vs baseline: 1.3944x; 1.2740x over previous
//
#include <hip/hip_runtime.h>
#include <math.h>

#define NN 50000
#define NE 800000
#define KD 128
#define SLOPE 0.22916666666666666f  /* 11/48, torch RReLU eval negative slope */
#define SCAN_NB 196                 /* ceil(NN/256) */

__device__ __forceinline__ void fma4(float s, const float4& q, float4& acc){
  acc.x = fmaf(s, q.x, acc.x); acc.y = fmaf(s, q.y, acc.y);
  acc.z = fmaf(s, q.z, acc.z); acc.w = fmaf(s, q.w, acc.w);
}

// ---------------------------------------------------------------------------
// Evolve, kernel A: T[layer][g] = Mg @ Q, Mg = gW[g] + (g<2 ? gU[g] : 0).
// Grid: 24 blocks = layer(2) x {gate(3) x rowhalf(2)} x colhalf(2).
// ---------------------------------------------------------------------------
__global__ __launch_bounds__(256) void evolveA_kernel(
    const float* __restrict__ gW_0, const float* __restrict__ gU_0,
    const float* __restrict__ gW_1, const float* __restrict__ gU_1,
    const float* __restrict__ Q_0, const float* __restrict__ Q_1,
    float* __restrict__ T)   // [2][3][128][128]
{
  __shared__ float4 sA[64*33];   // A-tile rows padded to 132 floats
  __shared__ float4 sQ[128*16];  // Q-tile [128][64]
  const int bx = blockIdx.x;
  const int layer = bx / 12;
  const int rt = (bx % 12) >> 1;
  const int ct = bx & 1;
  const int gate = rt >> 1;
  const int rbase = (rt & 1) * 64;
  const int tid = threadIdx.x;
  const float4* gW4 = (const float4*)(layer ? gW_1 : gW_0);
  const float4* gU4 = (const float4*)(layer ? gU_1 : gU_0);
  const float4* Q4  = (const float4*)(layer ? Q_1  : Q_0);

#pragma unroll
  for (int s = 0; s < 8; ++s){
    int ch = tid + 256*s;                    // 2048 chunks: 64 rows x 32
    int r = ch >> 5, c = ch & 31;
    int goff = gate*4096 + (rbase + r)*32 + c;
    float4 a = gW4[goff];
    if (gate < 2){ float4 u = gU4[goff]; a.x+=u.x; a.y+=u.y; a.z+=u.z; a.w+=u.w; }
    sA[r*33 + c] = a;
  }
#pragma unroll
  for (int s = 0; s < 8; ++s){
    int ch = tid + 256*s;                    // 2048 chunks: 128 rows x 16
    int kr = ch >> 4, qc = ch & 15;
    sQ[kr*16 + qc] = Q4[kr*32 + ct*16 + qc];
  }
  __syncthreads();

  const int it = tid & 15, jt = tid >> 4;
  float4 acc[4];
  acc[0]=acc[1]=acc[2]=acc[3]=make_float4(0.f,0.f,0.f,0.f);
  const float* sAf = (const float*)sA;
#pragma unroll 4
  for (int kq = 0; kq < 32; ++kq){
    float4 q0 = sQ[(kq*4+0)*16 + jt];
    float4 q1 = sQ[(kq*4+1)*16 + jt];
    float4 q2 = sQ[(kq*4+2)*16 + jt];
    float4 q3 = sQ[(kq*4+3)*16 + jt];
#pragma unroll
    for (int r = 0; r < 4; ++r){
      float4 a = *(const float4*)(sAf + (it*4+r)*132 + kq*4);
      fma4(a.x, q0, acc[r]); fma4(a.y, q1, acc[r]);
      fma4(a.z, q2, acc[r]); fma4(a.w, q3, acc[r]);
    }
  }
  float4* T4 = (float4*)T;
  const int tb = (layer*3 + gate)*4096;
#pragma unroll
  for (int r = 0; r < 4; ++r){
    int row = rbase + it*4 + r;
    T4[tb + row*32 + ct*16 + jt] = acc[r];
  }
}

// ---------------------------------------------------------------------------
// Evolve, kernel B: H = gU[2] @ (sigmoid(T1+b1) * Q); epilogue z/h/Q-update.
// ---------------------------------------------------------------------------
__global__ __launch_bounds__(256) void evolveB_kernel(
    const float* __restrict__ gU_0, const float* __restrict__ gU_1,
    const float* __restrict__ gb_0, const float* __restrict__ gb_1,
    const float* __restrict__ T,
    const float* __restrict__ Q_0, const float* __restrict__ Q_1,
    float* __restrict__ Qd_0, float* __restrict__ Qd_1)
{
  __shared__ float4 sA[64*33];
  __shared__ float4 sQ[128*16];
  const int bx = blockIdx.x;
  const int layer = bx >> 2;
  const int rt = (bx >> 1) & 1;
  const int ct = bx & 1;
  const int rbase = rt * 64;
  const int tid = threadIdx.x;
  const float4* gU4 = (const float4*)(layer ? gU_1 : gU_0);
  const float4* gb4 = (const float4*)(layer ? gb_1 : gb_0);
  const float4* Q4  = (const float4*)(layer ? Q_1  : Q_0);
  const float4* T4  = (const float4*)T;
  float4* Qd4 = (float4*)(layer ? Qd_1 : Qd_0);

#pragma unroll
  for (int s = 0; s < 8; ++s){
    int ch = tid + 256*s;
    int r = ch >> 5, c = ch & 31;
    sA[r*33 + c] = gU4[2*4096 + (rbase + r)*32 + c];
  }
#pragma unroll
  for (int s = 0; s < 8; ++s){
    int ch = tid + 256*s;
    int kr = ch >> 4, qc = ch & 15;
    int fo = kr*32 + ct*16 + qc;
    float4 t1 = T4[(layer*3+1)*4096 + fo];
    float4 b1 = gb4[1*4096 + fo];
    float4 q  = Q4[fo];
    float4 rq;
    rq.x = q.x / (1.f + expf(-(t1.x + b1.x)));
    rq.y = q.y / (1.f + expf(-(t1.y + b1.y)));
    rq.z = q.z / (1.f + expf(-(t1.z + b1.z)));
    rq.w = q.w / (1.f + expf(-(t1.w + b1.w)));
    sQ[kr*16 + qc] = rq;
  }
  __syncthreads();

  const int it = tid & 15, jt = tid >> 4;
  float4 acc[4];
  acc[0]=acc[1]=acc[2]=acc[3]=make_float4(0.f,0.f,0.f,0.f);
  const float* sAf = (const float*)sA;
#pragma unroll 4
  for (int kq = 0; kq < 32; ++kq){
    float4 q0 = sQ[(kq*4+0)*16 + jt];
    float4 q1 = sQ[(kq*4+1)*16 + jt];
    float4 q2 = sQ[(kq*4+2)*16 + jt];
    float4 q3 = sQ[(kq*4+3)*16 + jt];
#pragma unroll
    for (int r = 0; r < 4; ++r){
      float4 a = *(const float4*)(sAf + (it*4+r)*132 + kq*4);
      fma4(a.x, q0, acc[r]); fma4(a.y, q1, acc[r]);
      fma4(a.z, q2, acc[r]); fma4(a.w, q3, acc[r]);
    }
  }
#pragma unroll
  for (int r = 0; r < 4; ++r){
    int row = rbase + it*4 + r;
    int fo = row*32 + ct*16 + jt;
    float4 t0 = T4[(layer*3+0)*4096 + fo];
    float4 b0 = gb4[0*4096 + fo];
    float4 t2 = T4[(layer*3+2)*4096 + fo];
    float4 b2 = gb4[2*4096 + fo];
    float4 q  = Q4[fo];
    float4 o;
    { float z = 1.f/(1.f + expf(-(t0.x + b0.x)));
      float h = tanhf(t2.x + b2.x + acc[r].x);
      o.x = (1.f - z)*q.x + z*h; }
    { float z = 1.f/(1.f + expf(-(t0.y + b0.y)));
      float h = tanhf(t2.y + b2.y + acc[r].y);
      o.y = (1.f - z)*q.y + z*h; }
    { float z = 1.f/(1.f + expf(-(t0.z + b0.z)));
      float h = tanhf(t2.z + b2.z + acc[r].z);
      o.z = (1.f - z)*q.z + z*h; }
    { float z = 1.f/(1.f + expf(-(t0.w + b0.w)));
      float h = tanhf(t2.w + b2.w + acc[r].w);
      o.w = (1.f - z)*q.w + z*h; }
    Qd4[fo] = o;
  }
}

// ---------------------------------------------------------------------------
// GEMM: Y[nrows x 128] = X[nrows x 128] @ W[128 x 128], fp32 vector ALU.
// ---------------------------------------------------------------------------
__device__ __forceinline__ int wperm(int c){
  return ((c >> 1) & 7) | ((c & 1) << 3) | ((c >> 4) << 4);
}

__global__ __launch_bounds__(512) void gemm_kernel(
    const float* __restrict__ X, const float* __restrict__ W,
    float* __restrict__ Y, int nrows)
{
  __shared__ float4 sX4[128*33];   // row stride 132 floats
  __shared__ float4 sW4[128*32];
  const int tid = threadIdx.x;
  const int rg = tid >> 4;
  const int cg = tid & 15;
  const int rbase = blockIdx.x * 128;

  const float4* X4 = (const float4*)X;
  const float4* W4 = (const float4*)W;
#pragma unroll
  for (int s = 0; s < 8; ++s){
    int g4 = tid + 512*s;
    int r = g4 >> 5, c = g4 & 31;
    float4 v = make_float4(0.f,0.f,0.f,0.f);
    int row = rbase + r;
    if (row < nrows) v = X4[(size_t)row*32 + c];
    sX4[r*33 + c] = v;
  }
#pragma unroll
  for (int s = 0; s < 8; ++s){
    int g4 = tid + 512*s;
    int k = g4 >> 5, c = g4 & 31;
    sW4[k*32 + wperm(c)] = W4[g4];
  }
  __syncthreads();

  const float* sXf = (const float*)sX4;
  const int slotA = (cg & 7) | ((cg >> 3) << 4);
  const int slotB = slotA | 8;
  float acc[4][8];
#pragma unroll
  for (int a = 0; a < 4; ++a)
#pragma unroll
    for (int b = 0; b < 8; ++b) acc[a][b] = 0.f;

#pragma unroll 8
  for (int k = 0; k < 128; ++k){
    float4 wa = sW4[k*32 + slotA];
    float4 wb = sW4[k*32 + slotB];
#pragma unroll
    for (int rr = 0; rr < 4; ++rr){
      float xv = sXf[(rg*4 + rr)*132 + k];
      acc[rr][0] = fmaf(xv, wa.x, acc[rr][0]);
      acc[rr][1] = fmaf(xv, wa.y, acc[rr][1]);
      acc[rr][2] = fmaf(xv, wa.z, acc[rr][2]);
      acc[rr][3] = fmaf(xv, wa.w, acc[rr][3]);
      acc[rr][4] = fmaf(xv, wb.x, acc[rr][4]);
      acc[rr][5] = fmaf(xv, wb.y, acc[rr][5]);
      acc[rr][6] = fmaf(xv, wb.z, acc[rr][6]);
      acc[rr][7] = fmaf(xv, wb.w, acc[rr][7]);
    }
  }

  float4* Y4 = (float4*)Y;
#pragma unroll
  for (int rr = 0; rr < 4; ++rr){
    int row = rbase + rg*4 + rr;
    if (row < nrows){
      Y4[(size_t)row*32 + cg*2 + 0] = make_float4(acc[rr][0],acc[rr][1],acc[rr][2],acc[rr][3]);
      Y4[(size_t)row*32 + cg*2 + 1] = make_float4(acc[rr][4],acc[rr][5],acc[rr][6],acc[rr][7]);
    }
  }
}

// ---------------------------------------------------------------------------
// Edge binning: histogram -> 3-phase multi-block exclusive scan -> scatter.
// ---------------------------------------------------------------------------
__global__ __launch_bounds__(256) void hist_kernel(const int* __restrict__ row, int* __restrict__ counts){
  int idx = blockIdx.x*blockDim.x + threadIdx.x;
  int stride = gridDim.x*blockDim.x;
  for (int e = idx; e < NE; e += stride) atomicAdd(&counts[row[e]], 1);
}

__global__ __launch_bounds__(256) void scan1_kernel(const int* __restrict__ counts, int* __restrict__ blockSums){
  __shared__ int sb[256];
  int t = threadIdx.x;
  int idx = blockIdx.x*256 + t;
  sb[t] = (idx < NN) ? counts[idx] : 0;
  __syncthreads();
#pragma unroll
  for (int off = 128; off > 0; off >>= 1){
    if (t < off) sb[t] += sb[t + off];
    __syncthreads();
  }
  if (t == 0) blockSums[blockIdx.x] = sb[0];
}

__global__ __launch_bounds__(256) void scan2_kernel(const int* __restrict__ blockSums,
                                                    int* __restrict__ blockOffs, int* __restrict__ starts){
  __shared__ int sb[256];
  int t = threadIdx.x;
  int v = (t < SCAN_NB) ? blockSums[t] : 0;
  sb[t] = v;
  __syncthreads();
#pragma unroll
  for (int off = 1; off < 256; off <<= 1){
    int x = sb[t];
    int add = (t >= off) ? sb[t - off] : 0;
    __syncthreads();
    sb[t] = x + add;
    __syncthreads();
  }
  blockOffs[t] = sb[t] - v;            // exclusive prefix of block sums
  if (t == 255) starts[NN] = sb[255];  // total = NE
}

__global__ __launch_bounds__(256) void scan3_kernel(const int* __restrict__ counts, const int* __restrict__ blockOffs,
                                                    int* __restrict__ starts, int* __restrict__ cursors){
  __shared__ int sb[256];
  int t = threadIdx.x;
  int idx = blockIdx.x*256 + t;
  int v = (idx < NN) ? counts[idx] : 0;
  sb[t] = v;
  __syncthreads();
#pragma unroll
  for (int off = 1; off < 256; off <<= 1){
    int x = sb[t];
    int add = (t >= off) ? sb[t - off] : 0;
    __syncthreads();
    sb[t] = x + add;
    __syncthreads();
  }
  int pre = blockOffs[blockIdx.x] + sb[t] - v;   // global exclusive prefix
  if (idx < NN){ starts[idx] = pre; cursors[idx] = pre; }
}

__global__ __launch_bounds__(256) void scatter_kernel(const int* __restrict__ row, const int* __restrict__ col,
                                                      const float* __restrict__ val, int* __restrict__ cursors,
                                                      int* __restrict__ sCol, float* __restrict__ sVal){
  int idx = blockIdx.x*blockDim.x + threadIdx.x;
  int stride = gridDim.x*blockDim.x;
  for (int e = idx; e < NE; e += stride){
    int r = row[e];
    int p = atomicAdd(&cursors[r], 1);
    sCol[p] = col[e];
    sVal[p] = val[e];
  }
}

// ---------------------------------------------------------------------------
// SpMM: one 128-thread block per output row; thread j owns column j.
// ---------------------------------------------------------------------------
__global__ __launch_bounds__(128) void spmm_kernel(const int* __restrict__ starts, const int* __restrict__ sCol,
                                                   const float* __restrict__ sVal, const float* __restrict__ Y,
                                                   float* __restrict__ out){
  int r = blockIdx.x;
  int j = threadIdx.x;
  int e0 = starts[r], e1 = starts[r+1];
  float acc = 0.f;
  for (int e = e0; e < e1; ++e){
    int c = sCol[e];
    float v = sVal[e];
    acc = fmaf(v, Y[(size_t)c*KD + j], acc);
  }
  out[(size_t)r*KD + j] = (acc >= 0.f) ? acc : acc * SLOPE;
}

// ---------------------------------------------------------------------------
extern "C" void kernel_launch(void* const* d_in, const int* in_sizes, int n_in,
                              void* d_out, int out_size, void* d_ws, size_t ws_size,
                              hipStream_t stream)
{
  const float* features = (const float*)d_in[0];
  const int*   adj_row  = (const int*)d_in[1];
  const int*   adj_col  = (const int*)d_in[2];
  const float* adj_val  = (const float*)d_in[3];
  const float* W1  = (const float*)d_in[4];
  const float* g1W = (const float*)d_in[5];
  const float* g1U = (const float*)d_in[6];
  const float* g1b = (const float*)d_in[7];
  const float* W2  = (const float*)d_in[8];
  const float* g2W = (const float*)d_in[9];
  const float* g2U = (const float*)d_in[10];
  const float* g2b = (const float*)d_in[11];

  // only timestep T-1 ever reaches the output
  const float* feat3 = features + (size_t)3*NN*KD;
  const int*   row3  = adj_row + (size_t)3*NE;
  const int*   col3  = adj_col + (size_t)3*NE;
  const float* val3  = adj_val + (size_t)3*NE;

  float* ws    = (float*)d_ws;
  float* QP    = ws;                      // ping-pong Q: [2 bufs][2 layers][16384]
  float* Tbuf  = QP + 65536;              // [2][3][16384] = 98304
  int* counts  = (int*)(Tbuf + 98304);    // 50000 (padded 50016)
  int* starts  = counts + 50016;
  int* cursors = starts + 50016;
  int* blockSums = cursors + 50016;       // 256
  int* blockOffs = blockSums + 256;       // 256
  int* sCol    = blockOffs + 256;         // 800000
  float* sVal  = (float*)(sCol + NE);     // 800000
  float* XW    = sVal + NE;               // 6,400,000 (25.6 MB)
  float* outF  = (float*)d_out;

  float* QA0 = QP;           float* QA1 = QP + 16384;   // buffer A (layers 0,1)
  float* QB0 = QP + 32768;   float* QB1 = QP + 49152;   // buffer B

  hipMemsetAsync(counts, 0, NN*sizeof(int), stream);
  hist_kernel<<<1024, 256, 0, stream>>>(row3, counts);
  scan1_kernel<<<SCAN_NB, 256, 0, stream>>>(counts, blockSums);
  scan2_kernel<<<1, 256, 0, stream>>>(blockSums, blockOffs, starts);
  scan3_kernel<<<SCAN_NB, 256, 0, stream>>>(counts, blockOffs, starts, cursors);
  scatter_kernel<<<1024, 256, 0, stream>>>(row3, col3, val3, cursors, sCol, sVal);

  // GRU^4 on both layers' weights: iter0 reads W1/W2, then ping-pong A<->B.
  evolveA_kernel<<<24, 256, 0, stream>>>(g1W,g1U,g2W,g2U, W1,  W2,  Tbuf);
  evolveB_kernel<<< 8, 256, 0, stream>>>(g1U,g2U,g1b,g2b, Tbuf, W1,  W2,  QA0, QA1);
  evolveA_kernel<<<24, 256, 0, stream>>>(g1W,g1U,g2W,g2U, QA0, QA1, Tbuf);
  evolveB_kernel<<< 8, 256, 0, stream>>>(g1U,g2U,g1b,g2b, Tbuf, QA0, QA1, QB0, QB1);
  evolveA_kernel<<<24, 256, 0, stream>>>(g1W,g1U,g2W,g2U, QB0, QB1, Tbuf);
  evolveB_kernel<<< 8, 256, 0, stream>>>(g1U,g2U,g1b,g2b, Tbuf, QB0, QB1, QA0, QA1);
  evolveA_kernel<<<24, 256, 0, stream>>>(g1W,g1U,g2W,g2U, QA0, QA1, Tbuf);
  evolveB_kernel<<< 8, 256, 0, stream>>>(g1U,g2U,g1b,g2b, Tbuf, QA0, QA1, QB0, QB1);
  // evolved weights: W1e = QB0, W2e = QB1

  gemm_kernel<<<(NN + 127)/128, 512, 0, stream>>>(feat3, QB0, XW, NN);   // X3 @ W1e
  spmm_kernel<<<NN, 128, 0, stream>>>(starts, sCol, sVal, XW, outF);     // h1 -> d_out
  gemm_kernel<<<(NN + 127)/128, 512, 0, stream>>>(outF, QB1, XW, NN);    // h1 @ W2e
  spmm_kernel<<<NN, 128, 0, stream>>>(starts, sCol, sVal, XW, outF);     // final -> d_out
}

// Round 5
// 366.441 us; speedup vs baseline: 1.6416x; 1.1773x over previous
//
#include <hip/hip_runtime.h>
#include <math.h>

#define NN 50000
#define NE 800000
#define KD 128
#define SLOPE 0.22916666666666666f  /* 11/48, torch RReLU eval negative slope */
#define SCAN_NB 196                 /* ceil(NN/256) */

__device__ __forceinline__ void fma4(float s, const float4& q, float4& acc){
  acc.x = fmaf(s, q.x, acc.x); acc.y = fmaf(s, q.y, acc.y);
  acc.z = fmaf(s, q.z, acc.z); acc.w = fmaf(s, q.w, acc.w);
}

// ---------------------------------------------------------------------------
// Evolve, kernel A: T[layer][g] = Mg @ Q, Mg = gW[g] + (g<2 ? gU[g] : 0).
// Grid: 24 blocks = layer(2) x {gate(3) x rowhalf(2)} x colhalf(2).
// ---------------------------------------------------------------------------
__global__ __launch_bounds__(256) void evolveA_kernel(
    const float* __restrict__ gW_0, const float* __restrict__ gU_0,
    const float* __restrict__ gW_1, const float* __restrict__ gU_1,
    const float* __restrict__ Q_0, const float* __restrict__ Q_1,
    float* __restrict__ T)   // [2][3][128][128]
{
  __shared__ float4 sA[64*33];   // A-tile rows padded to 132 floats
  __shared__ float4 sQ[128*16];  // Q-tile [128][64]
  const int bx = blockIdx.x;
  const int layer = bx / 12;
  const int rt = (bx % 12) >> 1;
  const int ct = bx & 1;
  const int gate = rt >> 1;
  const int rbase = (rt & 1) * 64;
  const int tid = threadIdx.x;
  const float4* gW4 = (const float4*)(layer ? gW_1 : gW_0);
  const float4* gU4 = (const float4*)(layer ? gU_1 : gU_0);
  const float4* Q4  = (const float4*)(layer ? Q_1  : Q_0);

#pragma unroll
  for (int s = 0; s < 8; ++s){
    int ch = tid + 256*s;                    // 2048 chunks: 64 rows x 32
    int r = ch >> 5, c = ch & 31;
    int goff = gate*4096 + (rbase + r)*32 + c;
    float4 a = gW4[goff];
    if (gate < 2){ float4 u = gU4[goff]; a.x+=u.x; a.y+=u.y; a.z+=u.z; a.w+=u.w; }
    sA[r*33 + c] = a;
  }
#pragma unroll
  for (int s = 0; s < 8; ++s){
    int ch = tid + 256*s;                    // 2048 chunks: 128 rows x 16
    int kr = ch >> 4, qc = ch & 15;
    sQ[kr*16 + qc] = Q4[kr*32 + ct*16 + qc];
  }
  __syncthreads();

  const int it = tid & 15, jt = tid >> 4;
  float4 acc[4];
  acc[0]=acc[1]=acc[2]=acc[3]=make_float4(0.f,0.f,0.f,0.f);
  const float* sAf = (const float*)sA;
#pragma unroll 4
  for (int kq = 0; kq < 32; ++kq){
    float4 q0 = sQ[(kq*4+0)*16 + jt];
    float4 q1 = sQ[(kq*4+1)*16 + jt];
    float4 q2 = sQ[(kq*4+2)*16 + jt];
    float4 q3 = sQ[(kq*4+3)*16 + jt];
#pragma unroll
    for (int r = 0; r < 4; ++r){
      float4 a = *(const float4*)(sAf + (it*4+r)*132 + kq*4);
      fma4(a.x, q0, acc[r]); fma4(a.y, q1, acc[r]);
      fma4(a.z, q2, acc[r]); fma4(a.w, q3, acc[r]);
    }
  }
  float4* T4 = (float4*)T;
  const int tb = (layer*3 + gate)*4096;
#pragma unroll
  for (int r = 0; r < 4; ++r){
    int row = rbase + it*4 + r;
    T4[tb + row*32 + ct*16 + jt] = acc[r];
  }
}

// ---------------------------------------------------------------------------
// Evolve, kernel B: H = gU[2] @ (sigmoid(T1+b1) * Q); epilogue z/h/Q-update.
// ---------------------------------------------------------------------------
__global__ __launch_bounds__(256) void evolveB_kernel(
    const float* __restrict__ gU_0, const float* __restrict__ gU_1,
    const float* __restrict__ gb_0, const float* __restrict__ gb_1,
    const float* __restrict__ T,
    const float* __restrict__ Q_0, const float* __restrict__ Q_1,
    float* __restrict__ Qd_0, float* __restrict__ Qd_1)
{
  __shared__ float4 sA[64*33];
  __shared__ float4 sQ[128*16];
  const int bx = blockIdx.x;
  const int layer = bx >> 2;
  const int rt = (bx >> 1) & 1;
  const int ct = bx & 1;
  const int rbase = rt * 64;
  const int tid = threadIdx.x;
  const float4* gU4 = (const float4*)(layer ? gU_1 : gU_0);
  const float4* gb4 = (const float4*)(layer ? gb_1 : gb_0);
  const float4* Q4  = (const float4*)(layer ? Q_1  : Q_0);
  const float4* T4  = (const float4*)T;
  float4* Qd4 = (float4*)(layer ? Qd_1 : Qd_0);

#pragma unroll
  for (int s = 0; s < 8; ++s){
    int ch = tid + 256*s;
    int r = ch >> 5, c = ch & 31;
    sA[r*33 + c] = gU4[2*4096 + (rbase + r)*32 + c];
  }
#pragma unroll
  for (int s = 0; s < 8; ++s){
    int ch = tid + 256*s;
    int kr = ch >> 4, qc = ch & 15;
    int fo = kr*32 + ct*16 + qc;
    float4 t1 = T4[(layer*3+1)*4096 + fo];
    float4 b1 = gb4[1*4096 + fo];
    float4 q  = Q4[fo];
    float4 rq;
    rq.x = q.x / (1.f + expf(-(t1.x + b1.x)));
    rq.y = q.y / (1.f + expf(-(t1.y + b1.y)));
    rq.z = q.z / (1.f + expf(-(t1.z + b1.z)));
    rq.w = q.w / (1.f + expf(-(t1.w + b1.w)));
    sQ[kr*16 + qc] = rq;
  }
  __syncthreads();

  const int it = tid & 15, jt = tid >> 4;
  float4 acc[4];
  acc[0]=acc[1]=acc[2]=acc[3]=make_float4(0.f,0.f,0.f,0.f);
  const float* sAf = (const float*)sA;
#pragma unroll 4
  for (int kq = 0; kq < 32; ++kq){
    float4 q0 = sQ[(kq*4+0)*16 + jt];
    float4 q1 = sQ[(kq*4+1)*16 + jt];
    float4 q2 = sQ[(kq*4+2)*16 + jt];
    float4 q3 = sQ[(kq*4+3)*16 + jt];
#pragma unroll
    for (int r = 0; r < 4; ++r){
      float4 a = *(const float4*)(sAf + (it*4+r)*132 + kq*4);
      fma4(a.x, q0, acc[r]); fma4(a.y, q1, acc[r]);
      fma4(a.z, q2, acc[r]); fma4(a.w, q3, acc[r]);
    }
  }
#pragma unroll
  for (int r = 0; r < 4; ++r){
    int row = rbase + it*4 + r;
    int fo = row*32 + ct*16 + jt;
    float4 t0 = T4[(layer*3+0)*4096 + fo];
    float4 b0 = gb4[0*4096 + fo];
    float4 t2 = T4[(layer*3+2)*4096 + fo];
    float4 b2 = gb4[2*4096 + fo];
    float4 q  = Q4[fo];
    float4 o;
    { float z = 1.f/(1.f + expf(-(t0.x + b0.x)));
      float h = tanhf(t2.x + b2.x + acc[r].x);
      o.x = (1.f - z)*q.x + z*h; }
    { float z = 1.f/(1.f + expf(-(t0.y + b0.y)));
      float h = tanhf(t2.y + b2.y + acc[r].y);
      o.y = (1.f - z)*q.y + z*h; }
    { float z = 1.f/(1.f + expf(-(t0.z + b0.z)));
      float h = tanhf(t2.z + b2.z + acc[r].z);
      o.z = (1.f - z)*q.z + z*h; }
    { float z = 1.f/(1.f + expf(-(t0.w + b0.w)));
      float h = tanhf(t2.w + b2.w + acc[r].w);
      o.w = (1.f - z)*q.w + z*h; }
    Qd4[fo] = o;
  }
}

// ---------------------------------------------------------------------------
// GEMM: Y[nrows x 128] = X[nrows x 128] @ W[128 x 128], fp32 vector ALU.
// ---------------------------------------------------------------------------
__device__ __forceinline__ int wperm(int c){
  return ((c >> 1) & 7) | ((c & 1) << 3) | ((c >> 4) << 4);
}

__global__ __launch_bounds__(512) void gemm_kernel(
    const float* __restrict__ X, const float* __restrict__ W,
    float* __restrict__ Y, int nrows)
{
  __shared__ float4 sX4[128*33];   // row stride 132 floats
  __shared__ float4 sW4[128*32];
  const int tid = threadIdx.x;
  const int rg = tid >> 4;
  const int cg = tid & 15;
  const int rbase = blockIdx.x * 128;

  const float4* X4 = (const float4*)X;
  const float4* W4 = (const float4*)W;
#pragma unroll
  for (int s = 0; s < 8; ++s){
    int g4 = tid + 512*s;
    int r = g4 >> 5, c = g4 & 31;
    float4 v = make_float4(0.f,0.f,0.f,0.f);
    int row = rbase + r;
    if (row < nrows) v = X4[(size_t)row*32 + c];
    sX4[r*33 + c] = v;
  }
#pragma unroll
  for (int s = 0; s < 8; ++s){
    int g4 = tid + 512*s;
    int k = g4 >> 5, c = g4 & 31;
    sW4[k*32 + wperm(c)] = W4[g4];
  }
  __syncthreads();

  const float* sXf = (const float*)sX4;
  const int slotA = (cg & 7) | ((cg >> 3) << 4);
  const int slotB = slotA | 8;
  float acc[4][8];
#pragma unroll
  for (int a = 0; a < 4; ++a)
#pragma unroll
    for (int b = 0; b < 8; ++b) acc[a][b] = 0.f;

#pragma unroll 8
  for (int k = 0; k < 128; ++k){
    float4 wa = sW4[k*32 + slotA];
    float4 wb = sW4[k*32 + slotB];
#pragma unroll
    for (int rr = 0; rr < 4; ++rr){
      float xv = sXf[(rg*4 + rr)*132 + k];
      acc[rr][0] = fmaf(xv, wa.x, acc[rr][0]);
      acc[rr][1] = fmaf(xv, wa.y, acc[rr][1]);
      acc[rr][2] = fmaf(xv, wa.z, acc[rr][2]);
      acc[rr][3] = fmaf(xv, wa.w, acc[rr][3]);
      acc[rr][4] = fmaf(xv, wb.x, acc[rr][4]);
      acc[rr][5] = fmaf(xv, wb.y, acc[rr][5]);
      acc[rr][6] = fmaf(xv, wb.z, acc[rr][6]);
      acc[rr][7] = fmaf(xv, wb.w, acc[rr][7]);
    }
  }

  float4* Y4 = (float4*)Y;
#pragma unroll
  for (int rr = 0; rr < 4; ++rr){
    int row = rbase + rg*4 + rr;
    if (row < nrows){
      Y4[(size_t)row*32 + cg*2 + 0] = make_float4(acc[rr][0],acc[rr][1],acc[rr][2],acc[rr][3]);
      Y4[(size_t)row*32 + cg*2 + 1] = make_float4(acc[rr][4],acc[rr][5],acc[rr][6],acc[rr][7]);
    }
  }
}

// ---------------------------------------------------------------------------
// Edge binning: histogram -> 3-phase multi-block exclusive scan -> scatter.
// ---------------------------------------------------------------------------
__global__ __launch_bounds__(256) void hist_kernel(const int* __restrict__ row, int* __restrict__ counts){
  int idx = blockIdx.x*blockDim.x + threadIdx.x;
  int stride = gridDim.x*blockDim.x;
  for (int e = idx; e < NE; e += stride) atomicAdd(&counts[row[e]], 1);
}

__global__ __launch_bounds__(256) void scan1_kernel(const int* __restrict__ counts, int* __restrict__ blockSums){
  __shared__ int sb[256];
  int t = threadIdx.x;
  int idx = blockIdx.x*256 + t;
  sb[t] = (idx < NN) ? counts[idx] : 0;
  __syncthreads();
#pragma unroll
  for (int off = 128; off > 0; off >>= 1){
    if (t < off) sb[t] += sb[t + off];
    __syncthreads();
  }
  if (t == 0) blockSums[blockIdx.x] = sb[0];
}

__global__ __launch_bounds__(256) void scan2_kernel(const int* __restrict__ blockSums,
                                                    int* __restrict__ blockOffs, int* __restrict__ starts){
  __shared__ int sb[256];
  int t = threadIdx.x;
  int v = (t < SCAN_NB) ? blockSums[t] : 0;
  sb[t] = v;
  __syncthreads();
#pragma unroll
  for (int off = 1; off < 256; off <<= 1){
    int x = sb[t];
    int add = (t >= off) ? sb[t - off] : 0;
    __syncthreads();
    sb[t] = x + add;
    __syncthreads();
  }
  blockOffs[t] = sb[t] - v;            // exclusive prefix of block sums
  if (t == 255) starts[NN] = sb[255];  // total = NE
}

__global__ __launch_bounds__(256) void scan3_kernel(const int* __restrict__ counts, const int* __restrict__ blockOffs,
                                                    int* __restrict__ starts, int* __restrict__ cursors){
  __shared__ int sb[256];
  int t = threadIdx.x;
  int idx = blockIdx.x*256 + t;
  int v = (idx < NN) ? counts[idx] : 0;
  sb[t] = v;
  __syncthreads();
#pragma unroll
  for (int off = 1; off < 256; off <<= 1){
    int x = sb[t];
    int add = (t >= off) ? sb[t - off] : 0;
    __syncthreads();
    sb[t] = x + add;
    __syncthreads();
  }
  int pre = blockOffs[blockIdx.x] + sb[t] - v;   // global exclusive prefix
  if (idx < NN){ starts[idx] = pre; cursors[idx] = pre; }
}

__global__ __launch_bounds__(256) void scatter_kernel(const int* __restrict__ row, const int* __restrict__ col,
                                                      const float* __restrict__ val, int* __restrict__ cursors,
                                                      int* __restrict__ sCol, float* __restrict__ sVal){
  int idx = blockIdx.x*blockDim.x + threadIdx.x;
  int stride = gridDim.x*blockDim.x;
  for (int e = idx; e < NE; e += stride){
    int r = row[e];
    int p = atomicAdd(&cursors[r], 1);
    sCol[p] = col[e];
    sVal[p] = val[e];
  }
}

// ---------------------------------------------------------------------------
// SpMM: one WAVE per output row; lane j owns columns 2j,2j+1 (float2).
// Edge loop unrolled x8/x4 so up to 8 independent 512B row-gathers are in
// flight per wave (latency hiding). Accumulation order per element is
// unchanged (sequential in bin order). rrelu fused into writeback.
// ---------------------------------------------------------------------------
__global__ __launch_bounds__(256) void spmm_kernel(const int* __restrict__ starts, const int* __restrict__ sCol,
                                                   const float* __restrict__ sVal, const float* __restrict__ Y,
                                                   float* __restrict__ out){
  const int w = threadIdx.x >> 6;          // wave in block
  const int lane = threadIdx.x & 63;
  const int r = blockIdx.x*4 + w;
  if (r >= NN) return;
  const int e0 = starts[r], e1 = starts[r+1];
  const float2* __restrict__ Y2 = (const float2*)Y;
  float2 acc = make_float2(0.f, 0.f);
  int e = e0;
  for (; e + 8 <= e1; e += 8){
    int   c0 = sCol[e+0], c1 = sCol[e+1], c2 = sCol[e+2], c3 = sCol[e+3];
    int   c4 = sCol[e+4], c5 = sCol[e+5], c6 = sCol[e+6], c7 = sCol[e+7];
    float v0 = sVal[e+0], v1 = sVal[e+1], v2 = sVal[e+2], v3 = sVal[e+3];
    float v4 = sVal[e+4], v5 = sVal[e+5], v6 = sVal[e+6], v7 = sVal[e+7];
    float2 y0 = Y2[(size_t)c0*64 + lane];
    float2 y1 = Y2[(size_t)c1*64 + lane];
    float2 y2 = Y2[(size_t)c2*64 + lane];
    float2 y3 = Y2[(size_t)c3*64 + lane];
    float2 y4 = Y2[(size_t)c4*64 + lane];
    float2 y5 = Y2[(size_t)c5*64 + lane];
    float2 y6 = Y2[(size_t)c6*64 + lane];
    float2 y7 = Y2[(size_t)c7*64 + lane];
    acc.x = fmaf(v0, y0.x, acc.x); acc.y = fmaf(v0, y0.y, acc.y);
    acc.x = fmaf(v1, y1.x, acc.x); acc.y = fmaf(v1, y1.y, acc.y);
    acc.x = fmaf(v2, y2.x, acc.x); acc.y = fmaf(v2, y2.y, acc.y);
    acc.x = fmaf(v3, y3.x, acc.x); acc.y = fmaf(v3, y3.y, acc.y);
    acc.x = fmaf(v4, y4.x, acc.x); acc.y = fmaf(v4, y4.y, acc.y);
    acc.x = fmaf(v5, y5.x, acc.x); acc.y = fmaf(v5, y5.y, acc.y);
    acc.x = fmaf(v6, y6.x, acc.x); acc.y = fmaf(v6, y6.y, acc.y);
    acc.x = fmaf(v7, y7.x, acc.x); acc.y = fmaf(v7, y7.y, acc.y);
  }
  for (; e + 4 <= e1; e += 4){
    int   c0 = sCol[e+0], c1 = sCol[e+1], c2 = sCol[e+2], c3 = sCol[e+3];
    float v0 = sVal[e+0], v1 = sVal[e+1], v2 = sVal[e+2], v3 = sVal[e+3];
    float2 y0 = Y2[(size_t)c0*64 + lane];
    float2 y1 = Y2[(size_t)c1*64 + lane];
    float2 y2 = Y2[(size_t)c2*64 + lane];
    float2 y3 = Y2[(size_t)c3*64 + lane];
    acc.x = fmaf(v0, y0.x, acc.x); acc.y = fmaf(v0, y0.y, acc.y);
    acc.x = fmaf(v1, y1.x, acc.x); acc.y = fmaf(v1, y1.y, acc.y);
    acc.x = fmaf(v2, y2.x, acc.x); acc.y = fmaf(v2, y2.y, acc.y);
    acc.x = fmaf(v3, y3.x, acc.x); acc.y = fmaf(v3, y3.y, acc.y);
  }
  for (; e < e1; ++e){
    int c = sCol[e];
    float v = sVal[e];
    float2 y = Y2[(size_t)c*64 + lane];
    acc.x = fmaf(v, y.x, acc.x); acc.y = fmaf(v, y.y, acc.y);
  }
  float2 o;
  o.x = (acc.x >= 0.f) ? acc.x : acc.x * SLOPE;
  o.y = (acc.y >= 0.f) ? acc.y : acc.y * SLOPE;
  ((float2*)out)[(size_t)r*64 + lane] = o;
}

// ---------------------------------------------------------------------------
extern "C" void kernel_launch(void* const* d_in, const int* in_sizes, int n_in,
                              void* d_out, int out_size, void* d_ws, size_t ws_size,
                              hipStream_t stream)
{
  const float* features = (const float*)d_in[0];
  const int*   adj_row  = (const int*)d_in[1];
  const int*   adj_col  = (const int*)d_in[2];
  const float* adj_val  = (const float*)d_in[3];
  const float* W1  = (const float*)d_in[4];
  const float* g1W = (const float*)d_in[5];
  const float* g1U = (const float*)d_in[6];
  const float* g1b = (const float*)d_in[7];
  const float* W2  = (const float*)d_in[8];
  const float* g2W = (const float*)d_in[9];
  const float* g2U = (const float*)d_in[10];
  const float* g2b = (const float*)d_in[11];

  // only timestep T-1 ever reaches the output
  const float* feat3 = features + (size_t)3*NN*KD;
  const int*   row3  = adj_row + (size_t)3*NE;
  const int*   col3  = adj_col + (size_t)3*NE;
  const float* val3  = adj_val + (size_t)3*NE;

  float* ws    = (float*)d_ws;
  float* QP    = ws;                      // ping-pong Q: [2 bufs][2 layers][16384]
  float* Tbuf  = QP + 65536;              // [2][3][16384] = 98304
  int* counts  = (int*)(Tbuf + 98304);    // 50000 (padded 50016)
  int* starts  = counts + 50016;
  int* cursors = starts + 50016;
  int* blockSums = cursors + 50016;       // 256
  int* blockOffs = blockSums + 256;       // 256
  int* sCol    = blockOffs + 256;         // 800000
  float* sVal  = (float*)(sCol + NE);     // 800000
  float* XW    = sVal + NE;               // 6,400,000 (25.6 MB)
  float* outF  = (float*)d_out;

  float* QA0 = QP;           float* QA1 = QP + 16384;   // buffer A (layers 0,1)
  float* QB0 = QP + 32768;   float* QB1 = QP + 49152;   // buffer B

  hipMemsetAsync(counts, 0, NN*sizeof(int), stream);
  hist_kernel<<<1024, 256, 0, stream>>>(row3, counts);
  scan1_kernel<<<SCAN_NB, 256, 0, stream>>>(counts, blockSums);
  scan2_kernel<<<1, 256, 0, stream>>>(blockSums, blockOffs, starts);
  scan3_kernel<<<SCAN_NB, 256, 0, stream>>>(counts, blockOffs, starts, cursors);
  scatter_kernel<<<1024, 256, 0, stream>>>(row3, col3, val3, cursors, sCol, sVal);

  // GRU^4 on both layers' weights: iter0 reads W1/W2, then ping-pong A<->B.
  evolveA_kernel<<<24, 256, 0, stream>>>(g1W,g1U,g2W,g2U, W1,  W2,  Tbuf);
  evolveB_kernel<<< 8, 256, 0, stream>>>(g1U,g2U,g1b,g2b, Tbuf, W1,  W2,  QA0, QA1);
  evolveA_kernel<<<24, 256, 0, stream>>>(g1W,g1U,g2W,g2U, QA0, QA1, Tbuf);
  evolveB_kernel<<< 8, 256, 0, stream>>>(g1U,g2U,g1b,g2b, Tbuf, QA0, QA1, QB0, QB1);
  evolveA_kernel<<<24, 256, 0, stream>>>(g1W,g1U,g2W,g2U, QB0, QB1, Tbuf);
  evolveB_kernel<<< 8, 256, 0, stream>>>(g1U,g2U,g1b,g2b, Tbuf, QB0, QB1, QA0, QA1);
  evolveA_kernel<<<24, 256, 0, stream>>>(g1W,g1U,g2W,g2U, QA0, QA1, Tbuf);
  evolveB_kernel<<< 8, 256, 0, stream>>>(g1U,g2U,g1b,g2b, Tbuf, QA0, QA1, QB0, QB1);
  // evolved weights: W1e = QB0, W2e = QB1

  gemm_kernel<<<(NN + 127)/128, 512, 0, stream>>>(feat3, QB0, XW, NN);   // X3 @ W1e
  spmm_kernel<<<(NN + 3)/4, 256, 0, stream>>>(starts, sCol, sVal, XW, outF);   // h1 -> d_out
  gemm_kernel<<<(NN + 127)/128, 512, 0, stream>>>(outF, QB1, XW, NN);    // h1 @ W2e
  spmm_kernel<<<(NN + 3)/4, 256, 0, stream>>>(starts, sCol, sVal, XW, outF);   // final -> d_out
}

// Round 6
// 365.851 us; speedup vs baseline: 1.6442x; 1.0016x over previous
//
#include <hip/hip_runtime.h>
#include <math.h>

#define NN 50000
#define NE 800000
#define KD 128
#define SLOPE 0.22916666666666666f  /* 11/48, torch RReLU eval negative slope */
#define SCAN_NB 196                 /* ceil(NN/256) */

__device__ __forceinline__ void fma4(float s, const float4& q, float4& acc){
  acc.x = fmaf(s, q.x, acc.x); acc.y = fmaf(s, q.y, acc.y);
  acc.z = fmaf(s, q.z, acc.z); acc.w = fmaf(s, q.w, acc.w);
}

// ---------------------------------------------------------------------------
// Evolve, kernel A: T[layer][g] = Mg @ Q, Mg = gW[g] + (g<2 ? gU[g] : 0).
// Grid: 24 blocks = layer(2) x {gate(3) x rowhalf(2)} x colhalf(2).
// ---------------------------------------------------------------------------
__global__ __launch_bounds__(256) void evolveA_kernel(
    const float* __restrict__ gW_0, const float* __restrict__ gU_0,
    const float* __restrict__ gW_1, const float* __restrict__ gU_1,
    const float* __restrict__ Q_0, const float* __restrict__ Q_1,
    float* __restrict__ T)   // [2][3][128][128]
{
  __shared__ float4 sA[64*33];   // A-tile rows padded to 132 floats
  __shared__ float4 sQ[128*16];  // Q-tile [128][64]
  const int bx = blockIdx.x;
  const int layer = bx / 12;
  const int rt = (bx % 12) >> 1;
  const int ct = bx & 1;
  const int gate = rt >> 1;
  const int rbase = (rt & 1) * 64;
  const int tid = threadIdx.x;
  const float4* gW4 = (const float4*)(layer ? gW_1 : gW_0);
  const float4* gU4 = (const float4*)(layer ? gU_1 : gU_0);
  const float4* Q4  = (const float4*)(layer ? Q_1  : Q_0);

#pragma unroll
  for (int s = 0; s < 8; ++s){
    int ch = tid + 256*s;                    // 2048 chunks: 64 rows x 32
    int r = ch >> 5, c = ch & 31;
    int goff = gate*4096 + (rbase + r)*32 + c;
    float4 a = gW4[goff];
    if (gate < 2){ float4 u = gU4[goff]; a.x+=u.x; a.y+=u.y; a.z+=u.z; a.w+=u.w; }
    sA[r*33 + c] = a;
  }
#pragma unroll
  for (int s = 0; s < 8; ++s){
    int ch = tid + 256*s;                    // 2048 chunks: 128 rows x 16
    int kr = ch >> 4, qc = ch & 15;
    sQ[kr*16 + qc] = Q4[kr*32 + ct*16 + qc];
  }
  __syncthreads();

  const int it = tid & 15, jt = tid >> 4;
  float4 acc[4];
  acc[0]=acc[1]=acc[2]=acc[3]=make_float4(0.f,0.f,0.f,0.f);
  const float* sAf = (const float*)sA;
#pragma unroll 4
  for (int kq = 0; kq < 32; ++kq){
    float4 q0 = sQ[(kq*4+0)*16 + jt];
    float4 q1 = sQ[(kq*4+1)*16 + jt];
    float4 q2 = sQ[(kq*4+2)*16 + jt];
    float4 q3 = sQ[(kq*4+3)*16 + jt];
#pragma unroll
    for (int r = 0; r < 4; ++r){
      float4 a = *(const float4*)(sAf + (it*4+r)*132 + kq*4);
      fma4(a.x, q0, acc[r]); fma4(a.y, q1, acc[r]);
      fma4(a.z, q2, acc[r]); fma4(a.w, q3, acc[r]);
    }
  }
  float4* T4 = (float4*)T;
  const int tb = (layer*3 + gate)*4096;
#pragma unroll
  for (int r = 0; r < 4; ++r){
    int row = rbase + it*4 + r;
    T4[tb + row*32 + ct*16 + jt] = acc[r];
  }
}

// ---------------------------------------------------------------------------
// Evolve, kernel B: H = gU[2] @ (sigmoid(T1+b1) * Q); epilogue z/h/Q-update.
// ---------------------------------------------------------------------------
__global__ __launch_bounds__(256) void evolveB_kernel(
    const float* __restrict__ gU_0, const float* __restrict__ gU_1,
    const float* __restrict__ gb_0, const float* __restrict__ gb_1,
    const float* __restrict__ T,
    const float* __restrict__ Q_0, const float* __restrict__ Q_1,
    float* __restrict__ Qd_0, float* __restrict__ Qd_1)
{
  __shared__ float4 sA[64*33];
  __shared__ float4 sQ[128*16];
  const int bx = blockIdx.x;
  const int layer = bx >> 2;
  const int rt = (bx >> 1) & 1;
  const int ct = bx & 1;
  const int rbase = rt * 64;
  const int tid = threadIdx.x;
  const float4* gU4 = (const float4*)(layer ? gU_1 : gU_0);
  const float4* gb4 = (const float4*)(layer ? gb_1 : gb_0);
  const float4* Q4  = (const float4*)(layer ? Q_1  : Q_0);
  const float4* T4  = (const float4*)T;
  float4* Qd4 = (float4*)(layer ? Qd_1 : Qd_0);

#pragma unroll
  for (int s = 0; s < 8; ++s){
    int ch = tid + 256*s;
    int r = ch >> 5, c = ch & 31;
    sA[r*33 + c] = gU4[2*4096 + (rbase + r)*32 + c];
  }
#pragma unroll
  for (int s = 0; s < 8; ++s){
    int ch = tid + 256*s;
    int kr = ch >> 4, qc = ch & 15;
    int fo = kr*32 + ct*16 + qc;
    float4 t1 = T4[(layer*3+1)*4096 + fo];
    float4 b1 = gb4[1*4096 + fo];
    float4 q  = Q4[fo];
    float4 rq;
    rq.x = q.x / (1.f + expf(-(t1.x + b1.x)));
    rq.y = q.y / (1.f + expf(-(t1.y + b1.y)));
    rq.z = q.z / (1.f + expf(-(t1.z + b1.z)));
    rq.w = q.w / (1.f + expf(-(t1.w + b1.w)));
    sQ[kr*16 + qc] = rq;
  }
  __syncthreads();

  const int it = tid & 15, jt = tid >> 4;
  float4 acc[4];
  acc[0]=acc[1]=acc[2]=acc[3]=make_float4(0.f,0.f,0.f,0.f);
  const float* sAf = (const float*)sA;
#pragma unroll 4
  for (int kq = 0; kq < 32; ++kq){
    float4 q0 = sQ[(kq*4+0)*16 + jt];
    float4 q1 = sQ[(kq*4+1)*16 + jt];
    float4 q2 = sQ[(kq*4+2)*16 + jt];
    float4 q3 = sQ[(kq*4+3)*16 + jt];
#pragma unroll
    for (int r = 0; r < 4; ++r){
      float4 a = *(const float4*)(sAf + (it*4+r)*132 + kq*4);
      fma4(a.x, q0, acc[r]); fma4(a.y, q1, acc[r]);
      fma4(a.z, q2, acc[r]); fma4(a.w, q3, acc[r]);
    }
  }
#pragma unroll
  for (int r = 0; r < 4; ++r){
    int row = rbase + it*4 + r;
    int fo = row*32 + ct*16 + jt;
    float4 t0 = T4[(layer*3+0)*4096 + fo];
    float4 b0 = gb4[0*4096 + fo];
    float4 t2 = T4[(layer*3+2)*4096 + fo];
    float4 b2 = gb4[2*4096 + fo];
    float4 q  = Q4[fo];
    float4 o;
    { float z = 1.f/(1.f + expf(-(t0.x + b0.x)));
      float h = tanhf(t2.x + b2.x + acc[r].x);
      o.x = (1.f - z)*q.x + z*h; }
    { float z = 1.f/(1.f + expf(-(t0.y + b0.y)));
      float h = tanhf(t2.y + b2.y + acc[r].y);
      o.y = (1.f - z)*q.y + z*h; }
    { float z = 1.f/(1.f + expf(-(t0.z + b0.z)));
      float h = tanhf(t2.z + b2.z + acc[r].z);
      o.z = (1.f - z)*q.z + z*h; }
    { float z = 1.f/(1.f + expf(-(t0.w + b0.w)));
      float h = tanhf(t2.w + b2.w + acc[r].w);
      o.w = (1.f - z)*q.w + z*h; }
    Qd4[fo] = o;
  }
}

// ---------------------------------------------------------------------------
// GEMM: Y[nrows x 128] = X[nrows x 128] @ W[128 x 128], fp32 vector ALU.
// ---------------------------------------------------------------------------
__device__ __forceinline__ int wperm(int c){
  return ((c >> 1) & 7) | ((c & 1) << 3) | ((c >> 4) << 4);
}

__global__ __launch_bounds__(512) void gemm_kernel(
    const float* __restrict__ X, const float* __restrict__ W,
    float* __restrict__ Y, int nrows)
{
  __shared__ float4 sX4[128*33];   // row stride 132 floats
  __shared__ float4 sW4[128*32];
  const int tid = threadIdx.x;
  const int rg = tid >> 4;
  const int cg = tid & 15;
  const int rbase = blockIdx.x * 128;

  const float4* X4 = (const float4*)X;
  const float4* W4 = (const float4*)W;
#pragma unroll
  for (int s = 0; s < 8; ++s){
    int g4 = tid + 512*s;
    int r = g4 >> 5, c = g4 & 31;
    float4 v = make_float4(0.f,0.f,0.f,0.f);
    int row = rbase + r;
    if (row < nrows) v = X4[(size_t)row*32 + c];
    sX4[r*33 + c] = v;
  }
#pragma unroll
  for (int s = 0; s < 8; ++s){
    int g4 = tid + 512*s;
    int k = g4 >> 5, c = g4 & 31;
    sW4[k*32 + wperm(c)] = W4[g4];
  }
  __syncthreads();

  const float* sXf = (const float*)sX4;
  const int slotA = (cg & 7) | ((cg >> 3) << 4);
  const int slotB = slotA | 8;
  float acc[4][8];
#pragma unroll
  for (int a = 0; a < 4; ++a)
#pragma unroll
    for (int b = 0; b < 8; ++b) acc[a][b] = 0.f;

#pragma unroll 8
  for (int k = 0; k < 128; ++k){
    float4 wa = sW4[k*32 + slotA];
    float4 wb = sW4[k*32 + slotB];
#pragma unroll
    for (int rr = 0; rr < 4; ++rr){
      float xv = sXf[(rg*4 + rr)*132 + k];
      acc[rr][0] = fmaf(xv, wa.x, acc[rr][0]);
      acc[rr][1] = fmaf(xv, wa.y, acc[rr][1]);
      acc[rr][2] = fmaf(xv, wa.z, acc[rr][2]);
      acc[rr][3] = fmaf(xv, wa.w, acc[rr][3]);
      acc[rr][4] = fmaf(xv, wb.x, acc[rr][4]);
      acc[rr][5] = fmaf(xv, wb.y, acc[rr][5]);
      acc[rr][6] = fmaf(xv, wb.z, acc[rr][6]);
      acc[rr][7] = fmaf(xv, wb.w, acc[rr][7]);
    }
  }

  float4* Y4 = (float4*)Y;
#pragma unroll
  for (int rr = 0; rr < 4; ++rr){
    int row = rbase + rg*4 + rr;
    if (row < nrows){
      Y4[(size_t)row*32 + cg*2 + 0] = make_float4(acc[rr][0],acc[rr][1],acc[rr][2],acc[rr][3]);
      Y4[(size_t)row*32 + cg*2 + 1] = make_float4(acc[rr][4],acc[rr][5],acc[rr][6],acc[rr][7]);
    }
  }
}

// ---------------------------------------------------------------------------
// Edge binning: histogram -> 3-phase multi-block exclusive scan -> scatter.
// One edge per thread; (col,val) packed to a single 8B store.
// ---------------------------------------------------------------------------
__global__ __launch_bounds__(256) void hist_kernel(const int* __restrict__ row, int* __restrict__ counts){
  int e = blockIdx.x*256 + threadIdx.x;
  if (e < NE) atomicAdd(&counts[row[e]], 1);
}

__global__ __launch_bounds__(256) void scan1_kernel(const int* __restrict__ counts, int* __restrict__ blockSums){
  __shared__ int sb[256];
  int t = threadIdx.x;
  int idx = blockIdx.x*256 + t;
  sb[t] = (idx < NN) ? counts[idx] : 0;
  __syncthreads();
#pragma unroll
  for (int off = 128; off > 0; off >>= 1){
    if (t < off) sb[t] += sb[t + off];
    __syncthreads();
  }
  if (t == 0) blockSums[blockIdx.x] = sb[0];
}

__global__ __launch_bounds__(256) void scan2_kernel(const int* __restrict__ blockSums,
                                                    int* __restrict__ blockOffs, int* __restrict__ starts){
  __shared__ int sb[256];
  int t = threadIdx.x;
  int v = (t < SCAN_NB) ? blockSums[t] : 0;
  sb[t] = v;
  __syncthreads();
#pragma unroll
  for (int off = 1; off < 256; off <<= 1){
    int x = sb[t];
    int add = (t >= off) ? sb[t - off] : 0;
    __syncthreads();
    sb[t] = x + add;
    __syncthreads();
  }
  blockOffs[t] = sb[t] - v;            // exclusive prefix of block sums
  if (t == 255) starts[NN] = sb[255];  // total = NE
}

__global__ __launch_bounds__(256) void scan3_kernel(const int* __restrict__ counts, const int* __restrict__ blockOffs,
                                                    int* __restrict__ starts, int* __restrict__ cursors){
  __shared__ int sb[256];
  int t = threadIdx.x;
  int idx = blockIdx.x*256 + t;
  int v = (idx < NN) ? counts[idx] : 0;
  sb[t] = v;
  __syncthreads();
#pragma unroll
  for (int off = 1; off < 256; off <<= 1){
    int x = sb[t];
    int add = (t >= off) ? sb[t - off] : 0;
    __syncthreads();
    sb[t] = x + add;
    __syncthreads();
  }
  int pre = blockOffs[blockIdx.x] + sb[t] - v;   // global exclusive prefix
  if (idx < NN){ starts[idx] = pre; cursors[idx] = pre; }
}

__global__ __launch_bounds__(256) void scatter_kernel(const int* __restrict__ row, const int* __restrict__ col,
                                                      const float* __restrict__ val, int* __restrict__ cursors,
                                                      int2* __restrict__ sEdge){
  int e = blockIdx.x*256 + threadIdx.x;
  if (e >= NE) return;
  int r = row[e];
  int p = atomicAdd(&cursors[r], 1);
  int2 pk;
  pk.x = col[e];
  pk.y = __float_as_int(val[e]);
  sEdge[p] = pk;        // single 8B scattered store per edge
}

// ---------------------------------------------------------------------------
// SpMM: one WAVE per output row; lane j owns columns 2j,2j+1 (float2).
// Edge loop unrolled x8/x4: up to 8 independent 512B row-gathers in flight.
// ---------------------------------------------------------------------------
__global__ __launch_bounds__(256) void spmm_kernel(const int* __restrict__ starts, const int2* __restrict__ sEdge,
                                                   const float* __restrict__ Y, float* __restrict__ out){
  const int w = threadIdx.x >> 6;          // wave in block
  const int lane = threadIdx.x & 63;
  const int r = blockIdx.x*4 + w;
  if (r >= NN) return;
  const int e0 = starts[r], e1 = starts[r+1];
  const float2* __restrict__ Y2 = (const float2*)Y;
  float2 acc = make_float2(0.f, 0.f);
  int e = e0;
  for (; e + 8 <= e1; e += 8){
    int2 p0 = sEdge[e+0], p1 = sEdge[e+1], p2 = sEdge[e+2], p3 = sEdge[e+3];
    int2 p4 = sEdge[e+4], p5 = sEdge[e+5], p6 = sEdge[e+6], p7 = sEdge[e+7];
    float2 y0 = Y2[(size_t)p0.x*64 + lane];
    float2 y1 = Y2[(size_t)p1.x*64 + lane];
    float2 y2 = Y2[(size_t)p2.x*64 + lane];
    float2 y3 = Y2[(size_t)p3.x*64 + lane];
    float2 y4 = Y2[(size_t)p4.x*64 + lane];
    float2 y5 = Y2[(size_t)p5.x*64 + lane];
    float2 y6 = Y2[(size_t)p6.x*64 + lane];
    float2 y7 = Y2[(size_t)p7.x*64 + lane];
    float v0 = __int_as_float(p0.y), v1 = __int_as_float(p1.y);
    float v2 = __int_as_float(p2.y), v3 = __int_as_float(p3.y);
    float v4 = __int_as_float(p4.y), v5 = __int_as_float(p5.y);
    float v6 = __int_as_float(p6.y), v7 = __int_as_float(p7.y);
    acc.x = fmaf(v0, y0.x, acc.x); acc.y = fmaf(v0, y0.y, acc.y);
    acc.x = fmaf(v1, y1.x, acc.x); acc.y = fmaf(v1, y1.y, acc.y);
    acc.x = fmaf(v2, y2.x, acc.x); acc.y = fmaf(v2, y2.y, acc.y);
    acc.x = fmaf(v3, y3.x, acc.x); acc.y = fmaf(v3, y3.y, acc.y);
    acc.x = fmaf(v4, y4.x, acc.x); acc.y = fmaf(v4, y4.y, acc.y);
    acc.x = fmaf(v5, y5.x, acc.x); acc.y = fmaf(v5, y5.y, acc.y);
    acc.x = fmaf(v6, y6.x, acc.x); acc.y = fmaf(v6, y6.y, acc.y);
    acc.x = fmaf(v7, y7.x, acc.x); acc.y = fmaf(v7, y7.y, acc.y);
  }
  for (; e + 4 <= e1; e += 4){
    int2 p0 = sEdge[e+0], p1 = sEdge[e+1], p2 = sEdge[e+2], p3 = sEdge[e+3];
    float2 y0 = Y2[(size_t)p0.x*64 + lane];
    float2 y1 = Y2[(size_t)p1.x*64 + lane];
    float2 y2 = Y2[(size_t)p2.x*64 + lane];
    float2 y3 = Y2[(size_t)p3.x*64 + lane];
    float v0 = __int_as_float(p0.y), v1 = __int_as_float(p1.y);
    float v2 = __int_as_float(p2.y), v3 = __int_as_float(p3.y);
    acc.x = fmaf(v0, y0.x, acc.x); acc.y = fmaf(v0, y0.y, acc.y);
    acc.x = fmaf(v1, y1.x, acc.x); acc.y = fmaf(v1, y1.y, acc.y);
    acc.x = fmaf(v2, y2.x, acc.x); acc.y = fmaf(v2, y2.y, acc.y);
    acc.x = fmaf(v3, y3.x, acc.x); acc.y = fmaf(v3, y3.y, acc.y);
  }
  for (; e < e1; ++e){
    int2 pk = sEdge[e];
    float v = __int_as_float(pk.y);
    float2 y = Y2[(size_t)pk.x*64 + lane];
    acc.x = fmaf(v, y.x, acc.x); acc.y = fmaf(v, y.y, acc.y);
  }
  float2 o;
  o.x = (acc.x >= 0.f) ? acc.x : acc.x * SLOPE;
  o.y = (acc.y >= 0.f) ? acc.y : acc.y * SLOPE;
  ((float2*)out)[(size_t)r*64 + lane] = o;
}

// ---------------------------------------------------------------------------
extern "C" void kernel_launch(void* const* d_in, const int* in_sizes, int n_in,
                              void* d_out, int out_size, void* d_ws, size_t ws_size,
                              hipStream_t stream)
{
  const float* features = (const float*)d_in[0];
  const int*   adj_row  = (const int*)d_in[1];
  const int*   adj_col  = (const int*)d_in[2];
  const float* adj_val  = (const float*)d_in[3];
  const float* W1  = (const float*)d_in[4];
  const float* g1W = (const float*)d_in[5];
  const float* g1U = (const float*)d_in[6];
  const float* g1b = (const float*)d_in[7];
  const float* W2  = (const float*)d_in[8];
  const float* g2W = (const float*)d_in[9];
  const float* g2U = (const float*)d_in[10];
  const float* g2b = (const float*)d_in[11];

  // only timestep T-1 ever reaches the output
  const float* feat3 = features + (size_t)3*NN*KD;
  const int*   row3  = adj_row + (size_t)3*NE;
  const int*   col3  = adj_col + (size_t)3*NE;
  const float* val3  = adj_val + (size_t)3*NE;

  float* ws    = (float*)d_ws;
  float* QP    = ws;                      // ping-pong Q: [2 bufs][2 layers][16384]
  float* Tbuf  = QP + 65536;              // [2][3][16384] = 98304
  int* counts  = (int*)(Tbuf + 98304);    // 50000 (padded 50016)
  int* starts  = counts + 50016;
  int* cursors = starts + 50016;
  int* blockSums = cursors + 50016;       // 256
  int* blockOffs = blockSums + 256;       // 256
  int2* sEdge  = (int2*)(blockOffs + 256);   // 800000 x 8B (8B-aligned)
  float* XW    = (float*)(sEdge + NE);    // 6,400,000 (25.6 MB)
  float* outF  = (float*)d_out;

  float* QA0 = QP;           float* QA1 = QP + 16384;   // buffer A (layers 0,1)
  float* QB0 = QP + 32768;   float* QB1 = QP + 49152;   // buffer B

  hipMemsetAsync(counts, 0, NN*sizeof(int), stream);
  hist_kernel<<<(NE + 255)/256, 256, 0, stream>>>(row3, counts);
  scan1_kernel<<<SCAN_NB, 256, 0, stream>>>(counts, blockSums);
  scan2_kernel<<<1, 256, 0, stream>>>(blockSums, blockOffs, starts);
  scan3_kernel<<<SCAN_NB, 256, 0, stream>>>(counts, blockOffs, starts, cursors);
  scatter_kernel<<<(NE + 255)/256, 256, 0, stream>>>(row3, col3, val3, cursors, sEdge);

  // GRU^4 on both layers' weights: iter0 reads W1/W2, then ping-pong A<->B.
  evolveA_kernel<<<24, 256, 0, stream>>>(g1W,g1U,g2W,g2U, W1,  W2,  Tbuf);
  evolveB_kernel<<< 8, 256, 0, stream>>>(g1U,g2U,g1b,g2b, Tbuf, W1,  W2,  QA0, QA1);
  evolveA_kernel<<<24, 256, 0, stream>>>(g1W,g1U,g2W,g2U, QA0, QA1, Tbuf);
  evolveB_kernel<<< 8, 256, 0, stream>>>(g1U,g2U,g1b,g2b, Tbuf, QA0, QA1, QB0, QB1);
  evolveA_kernel<<<24, 256, 0, stream>>>(g1W,g1U,g2W,g2U, QB0, QB1, Tbuf);
  evolveB_kernel<<< 8, 256, 0, stream>>>(g1U,g2U,g1b,g2b, Tbuf, QB0, QB1, QA0, QA1);
  evolveA_kernel<<<24, 256, 0, stream>>>(g1W,g1U,g2W,g2U, QA0, QA1, Tbuf);
  evolveB_kernel<<< 8, 256, 0, stream>>>(g1U,g2U,g1b,g2b, Tbuf, QA0, QA1, QB0, QB1);
  // evolved weights: W1e = QB0, W2e = QB1

  gemm_kernel<<<(NN + 127)/128, 512, 0, stream>>>(feat3, QB0, XW, NN);       // X3 @ W1e
  spmm_kernel<<<(NN + 3)/4, 256, 0, stream>>>(starts, sEdge, XW, outF);      // h1 -> d_out
  gemm_kernel<<<(NN + 127)/128, 512, 0, stream>>>(outF, QB1, XW, NN);        // h1 @ W2e
  spmm_kernel<<<(NN + 3)/4, 256, 0, stream>>>(starts, sEdge, XW, outF);      // final -> d_out
}

// Round 7
// 330.386 us; speedup vs baseline: 1.8207x; 1.1073x over previous
//
#include <hip/hip_runtime.h>
#include <math.h>

#define NN 50000
#define NE 800000
#define KD 128
#define SLOPE 0.22916666666666666f  /* 11/48, torch RReLU eval negative slope */
#define SCAN_NB 196                 /* ceil(NN/256) */

__device__ __forceinline__ void fma4(float s, const float4& q, float4& acc){
  acc.x = fmaf(s, q.x, acc.x); acc.y = fmaf(s, q.y, acc.y);
  acc.z = fmaf(s, q.z, acc.z); acc.w = fmaf(s, q.w, acc.w);
}

// ---------------------------------------------------------------------------
// Evolve, kernel A: T[layer][g] = Mg @ Q, Mg = gW[g] + (g<2 ? gU[g] : 0).
// Grid: 24 blocks = layer(2) x {gate(3) x rowhalf(2)} x colhalf(2).
// ---------------------------------------------------------------------------
__global__ __launch_bounds__(256) void evolveA_kernel(
    const float* __restrict__ gW_0, const float* __restrict__ gU_0,
    const float* __restrict__ gW_1, const float* __restrict__ gU_1,
    const float* __restrict__ Q_0, const float* __restrict__ Q_1,
    float* __restrict__ T)   // [2][3][128][128]
{
  __shared__ float4 sA[64*33];   // A-tile rows padded to 132 floats
  __shared__ float4 sQ[128*16];  // Q-tile [128][64]
  const int bx = blockIdx.x;
  const int layer = bx / 12;
  const int rt = (bx % 12) >> 1;
  const int ct = bx & 1;
  const int gate = rt >> 1;
  const int rbase = (rt & 1) * 64;
  const int tid = threadIdx.x;
  const float4* gW4 = (const float4*)(layer ? gW_1 : gW_0);
  const float4* gU4 = (const float4*)(layer ? gU_1 : gU_0);
  const float4* Q4  = (const float4*)(layer ? Q_1  : Q_0);

#pragma unroll
  for (int s = 0; s < 8; ++s){
    int ch = tid + 256*s;                    // 2048 chunks: 64 rows x 32
    int r = ch >> 5, c = ch & 31;
    int goff = gate*4096 + (rbase + r)*32 + c;
    float4 a = gW4[goff];
    if (gate < 2){ float4 u = gU4[goff]; a.x+=u.x; a.y+=u.y; a.z+=u.z; a.w+=u.w; }
    sA[r*33 + c] = a;
  }
#pragma unroll
  for (int s = 0; s < 8; ++s){
    int ch = tid + 256*s;                    // 2048 chunks: 128 rows x 16
    int kr = ch >> 4, qc = ch & 15;
    sQ[kr*16 + qc] = Q4[kr*32 + ct*16 + qc];
  }
  __syncthreads();

  const int it = tid & 15, jt = tid >> 4;
  float4 acc[4];
  acc[0]=acc[1]=acc[2]=acc[3]=make_float4(0.f,0.f,0.f,0.f);
  const float* sAf = (const float*)sA;
#pragma unroll 4
  for (int kq = 0; kq < 32; ++kq){
    float4 q0 = sQ[(kq*4+0)*16 + jt];
    float4 q1 = sQ[(kq*4+1)*16 + jt];
    float4 q2 = sQ[(kq*4+2)*16 + jt];
    float4 q3 = sQ[(kq*4+3)*16 + jt];
#pragma unroll
    for (int r = 0; r < 4; ++r){
      float4 a = *(const float4*)(sAf + (it*4+r)*132 + kq*4);
      fma4(a.x, q0, acc[r]); fma4(a.y, q1, acc[r]);
      fma4(a.z, q2, acc[r]); fma4(a.w, q3, acc[r]);
    }
  }
  float4* T4 = (float4*)T;
  const int tb = (layer*3 + gate)*4096;
#pragma unroll
  for (int r = 0; r < 4; ++r){
    int row = rbase + it*4 + r;
    T4[tb + row*32 + ct*16 + jt] = acc[r];
  }
}

// ---------------------------------------------------------------------------
// Evolve, kernel B: H = gU[2] @ (sigmoid(T1+b1) * Q); epilogue z/h/Q-update.
// ---------------------------------------------------------------------------
__global__ __launch_bounds__(256) void evolveB_kernel(
    const float* __restrict__ gU_0, const float* __restrict__ gU_1,
    const float* __restrict__ gb_0, const float* __restrict__ gb_1,
    const float* __restrict__ T,
    const float* __restrict__ Q_0, const float* __restrict__ Q_1,
    float* __restrict__ Qd_0, float* __restrict__ Qd_1)
{
  __shared__ float4 sA[64*33];
  __shared__ float4 sQ[128*16];
  const int bx = blockIdx.x;
  const int layer = bx >> 2;
  const int rt = (bx >> 1) & 1;
  const int ct = bx & 1;
  const int rbase = rt * 64;
  const int tid = threadIdx.x;
  const float4* gU4 = (const float4*)(layer ? gU_1 : gU_0);
  const float4* gb4 = (const float4*)(layer ? gb_1 : gb_0);
  const float4* Q4  = (const float4*)(layer ? Q_1  : Q_0);
  const float4* T4  = (const float4*)T;
  float4* Qd4 = (float4*)(layer ? Qd_1 : Qd_0);

#pragma unroll
  for (int s = 0; s < 8; ++s){
    int ch = tid + 256*s;
    int r = ch >> 5, c = ch & 31;
    sA[r*33 + c] = gU4[2*4096 + (rbase + r)*32 + c];
  }
#pragma unroll
  for (int s = 0; s < 8; ++s){
    int ch = tid + 256*s;
    int kr = ch >> 4, qc = ch & 15;
    int fo = kr*32 + ct*16 + qc;
    float4 t1 = T4[(layer*3+1)*4096 + fo];
    float4 b1 = gb4[1*4096 + fo];
    float4 q  = Q4[fo];
    float4 rq;
    rq.x = q.x / (1.f + expf(-(t1.x + b1.x)));
    rq.y = q.y / (1.f + expf(-(t1.y + b1.y)));
    rq.z = q.z / (1.f + expf(-(t1.z + b1.z)));
    rq.w = q.w / (1.f + expf(-(t1.w + b1.w)));
    sQ[kr*16 + qc] = rq;
  }
  __syncthreads();

  const int it = tid & 15, jt = tid >> 4;
  float4 acc[4];
  acc[0]=acc[1]=acc[2]=acc[3]=make_float4(0.f,0.f,0.f,0.f);
  const float* sAf = (const float*)sA;
#pragma unroll 4
  for (int kq = 0; kq < 32; ++kq){
    float4 q0 = sQ[(kq*4+0)*16 + jt];
    float4 q1 = sQ[(kq*4+1)*16 + jt];
    float4 q2 = sQ[(kq*4+2)*16 + jt];
    float4 q3 = sQ[(kq*4+3)*16 + jt];
#pragma unroll
    for (int r = 0; r < 4; ++r){
      float4 a = *(const float4*)(sAf + (it*4+r)*132 + kq*4);
      fma4(a.x, q0, acc[r]); fma4(a.y, q1, acc[r]);
      fma4(a.z, q2, acc[r]); fma4(a.w, q3, acc[r]);
    }
  }
#pragma unroll
  for (int r = 0; r < 4; ++r){
    int row = rbase + it*4 + r;
    int fo = row*32 + ct*16 + jt;
    float4 t0 = T4[(layer*3+0)*4096 + fo];
    float4 b0 = gb4[0*4096 + fo];
    float4 t2 = T4[(layer*3+2)*4096 + fo];
    float4 b2 = gb4[2*4096 + fo];
    float4 q  = Q4[fo];
    float4 o;
    { float z = 1.f/(1.f + expf(-(t0.x + b0.x)));
      float h = tanhf(t2.x + b2.x + acc[r].x);
      o.x = (1.f - z)*q.x + z*h; }
    { float z = 1.f/(1.f + expf(-(t0.y + b0.y)));
      float h = tanhf(t2.y + b2.y + acc[r].y);
      o.y = (1.f - z)*q.y + z*h; }
    { float z = 1.f/(1.f + expf(-(t0.z + b0.z)));
      float h = tanhf(t2.z + b2.z + acc[r].z);
      o.z = (1.f - z)*q.z + z*h; }
    { float z = 1.f/(1.f + expf(-(t0.w + b0.w)));
      float h = tanhf(t2.w + b2.w + acc[r].w);
      o.w = (1.f - z)*q.w + z*h; }
    Qd4[fo] = o;
  }
}

// ---------------------------------------------------------------------------
// GEMM: Y[nrows x 128] = X[nrows x 128] @ W[128 x 128], fp32 vector ALU.
// ---------------------------------------------------------------------------
__device__ __forceinline__ int wperm(int c){
  return ((c >> 1) & 7) | ((c & 1) << 3) | ((c >> 4) << 4);
}

__global__ __launch_bounds__(512) void gemm_kernel(
    const float* __restrict__ X, const float* __restrict__ W,
    float* __restrict__ Y, int nrows)
{
  __shared__ float4 sX4[128*33];   // row stride 132 floats
  __shared__ float4 sW4[128*32];
  const int tid = threadIdx.x;
  const int rg = tid >> 4;
  const int cg = tid & 15;
  const int rbase = blockIdx.x * 128;

  const float4* X4 = (const float4*)X;
  const float4* W4 = (const float4*)W;
#pragma unroll
  for (int s = 0; s < 8; ++s){
    int g4 = tid + 512*s;
    int r = g4 >> 5, c = g4 & 31;
    float4 v = make_float4(0.f,0.f,0.f,0.f);
    int row = rbase + r;
    if (row < nrows) v = X4[(size_t)row*32 + c];
    sX4[r*33 + c] = v;
  }
#pragma unroll
  for (int s = 0; s < 8; ++s){
    int g4 = tid + 512*s;
    int k = g4 >> 5, c = g4 & 31;
    sW4[k*32 + wperm(c)] = W4[g4];
  }
  __syncthreads();

  const float* sXf = (const float*)sX4;
  const int slotA = (cg & 7) | ((cg >> 3) << 4);
  const int slotB = slotA | 8;
  float acc[4][8];
#pragma unroll
  for (int a = 0; a < 4; ++a)
#pragma unroll
    for (int b = 0; b < 8; ++b) acc[a][b] = 0.f;

#pragma unroll 8
  for (int k = 0; k < 128; ++k){
    float4 wa = sW4[k*32 + slotA];
    float4 wb = sW4[k*32 + slotB];
#pragma unroll
    for (int rr = 0; rr < 4; ++rr){
      float xv = sXf[(rg*4 + rr)*132 + k];
      acc[rr][0] = fmaf(xv, wa.x, acc[rr][0]);
      acc[rr][1] = fmaf(xv, wa.y, acc[rr][1]);
      acc[rr][2] = fmaf(xv, wa.z, acc[rr][2]);
      acc[rr][3] = fmaf(xv, wa.w, acc[rr][3]);
      acc[rr][4] = fmaf(xv, wb.x, acc[rr][4]);
      acc[rr][5] = fmaf(xv, wb.y, acc[rr][5]);
      acc[rr][6] = fmaf(xv, wb.z, acc[rr][6]);
      acc[rr][7] = fmaf(xv, wb.w, acc[rr][7]);
    }
  }

  float4* Y4 = (float4*)Y;
#pragma unroll
  for (int rr = 0; rr < 4; ++rr){
    int row = rbase + rg*4 + rr;
    if (row < nrows){
      Y4[(size_t)row*32 + cg*2 + 0] = make_float4(acc[rr][0],acc[rr][1],acc[rr][2],acc[rr][3]);
      Y4[(size_t)row*32 + cg*2 + 1] = make_float4(acc[rr][4],acc[rr][5],acc[rr][6],acc[rr][7]);
    }
  }
}

// ---------------------------------------------------------------------------
// Edge binning: hist (writes per-edge rank) -> scan1 -> fused scan3 -> scatter.
// Scatter is atomic-free: p = starts[row] + rank. 4 edges/thread for MLP.
// ---------------------------------------------------------------------------
__global__ __launch_bounds__(256) void hist_kernel(const int* __restrict__ row,
                                                   int* __restrict__ counts, int* __restrict__ rank){
  int base = blockIdx.x*1024 + threadIdx.x;
#pragma unroll
  for (int s = 0; s < 4; ++s){
    int e = base + 256*s;
    if (e < NE) rank[e] = atomicAdd(&counts[row[e]], 1);
  }
}

__global__ __launch_bounds__(256) void scan1_kernel(const int* __restrict__ counts, int* __restrict__ blockSums){
  __shared__ int sb[256];
  int t = threadIdx.x;
  int idx = blockIdx.x*256 + t;
  sb[t] = (idx < NN) ? counts[idx] : 0;
  __syncthreads();
#pragma unroll
  for (int off = 128; off > 0; off >>= 1){
    if (t < off) sb[t] += sb[t + off];
    __syncthreads();
  }
  if (t == 0) blockSums[blockIdx.x] = sb[0];
}

// fused: computes this block's global offset from blockSums, then local scan.
__global__ __launch_bounds__(256) void scan3_kernel(const int* __restrict__ counts,
                                                    const int* __restrict__ blockSums,
                                                    int* __restrict__ starts){
  __shared__ int sb[256];
  __shared__ int soff;
  int t = threadIdx.x;
  int part = (t < blockIdx.x) ? blockSums[t] : 0;   // blockIdx.x < SCAN_NB <= 256
  sb[t] = part;
  __syncthreads();
#pragma unroll
  for (int off = 128; off > 0; off >>= 1){
    if (t < off) sb[t] += sb[t + off];
    __syncthreads();
  }
  if (t == 0) soff = sb[0];
  __syncthreads();

  int idx = blockIdx.x*256 + t;
  int v = (idx < NN) ? counts[idx] : 0;
  sb[t] = v;
  __syncthreads();
#pragma unroll
  for (int off = 1; off < 256; off <<= 1){
    int x = sb[t];
    int add = (t >= off) ? sb[t - off] : 0;
    __syncthreads();
    sb[t] = x + add;
    __syncthreads();
  }
  if (idx < NN) starts[idx] = soff + sb[t] - v;
  if (blockIdx.x == 0 && t == 0) starts[NN] = NE;
}

__global__ __launch_bounds__(256) void scatter_kernel(const int* __restrict__ row, const int* __restrict__ col,
                                                      const float* __restrict__ val, const int* __restrict__ rank,
                                                      const int* __restrict__ starts, int2* __restrict__ sEdge){
  int base = blockIdx.x*1024 + threadIdx.x;
  int e[4], r[4], rk[4];
  bool ok[4];
#pragma unroll
  for (int s = 0; s < 4; ++s){
    e[s] = base + 256*s;
    ok[s] = e[s] < NE;
    r[s]  = ok[s] ? row[e[s]]  : 0;
    rk[s] = ok[s] ? rank[e[s]] : 0;
  }
  int p[4];
#pragma unroll
  for (int s = 0; s < 4; ++s) p[s] = (ok[s] ? starts[r[s]] : 0) + rk[s];
#pragma unroll
  for (int s = 0; s < 4; ++s){
    if (ok[s]){
      int2 pk;
      pk.x = col[e[s]];
      pk.y = __float_as_int(val[e[s]]);
      sEdge[p[s]] = pk;
    }
  }
}

// ---------------------------------------------------------------------------
// SpMM: one WAVE per output row; lane j owns columns 2j,2j+1 (float2).
// Edge loop unrolled x8/x4: up to 8 independent 512B row-gathers in flight.
// ---------------------------------------------------------------------------
__global__ __launch_bounds__(256) void spmm_kernel(const int* __restrict__ starts, const int2* __restrict__ sEdge,
                                                   const float* __restrict__ Y, float* __restrict__ out){
  const int w = threadIdx.x >> 6;          // wave in block
  const int lane = threadIdx.x & 63;
  const int r = blockIdx.x*4 + w;
  if (r >= NN) return;
  const int e0 = starts[r], e1 = starts[r+1];
  const float2* __restrict__ Y2 = (const float2*)Y;
  float2 acc = make_float2(0.f, 0.f);
  int e = e0;
  for (; e + 8 <= e1; e += 8){
    int2 p0 = sEdge[e+0], p1 = sEdge[e+1], p2 = sEdge[e+2], p3 = sEdge[e+3];
    int2 p4 = sEdge[e+4], p5 = sEdge[e+5], p6 = sEdge[e+6], p7 = sEdge[e+7];
    float2 y0 = Y2[(size_t)p0.x*64 + lane];
    float2 y1 = Y2[(size_t)p1.x*64 + lane];
    float2 y2 = Y2[(size_t)p2.x*64 + lane];
    float2 y3 = Y2[(size_t)p3.x*64 + lane];
    float2 y4 = Y2[(size_t)p4.x*64 + lane];
    float2 y5 = Y2[(size_t)p5.x*64 + lane];
    float2 y6 = Y2[(size_t)p6.x*64 + lane];
    float2 y7 = Y2[(size_t)p7.x*64 + lane];
    float v0 = __int_as_float(p0.y), v1 = __int_as_float(p1.y);
    float v2 = __int_as_float(p2.y), v3 = __int_as_float(p3.y);
    float v4 = __int_as_float(p4.y), v5 = __int_as_float(p5.y);
    float v6 = __int_as_float(p6.y), v7 = __int_as_float(p7.y);
    acc.x = fmaf(v0, y0.x, acc.x); acc.y = fmaf(v0, y0.y, acc.y);
    acc.x = fmaf(v1, y1.x, acc.x); acc.y = fmaf(v1, y1.y, acc.y);
    acc.x = fmaf(v2, y2.x, acc.x); acc.y = fmaf(v2, y2.y, acc.y);
    acc.x = fmaf(v3, y3.x, acc.x); acc.y = fmaf(v3, y3.y, acc.y);
    acc.x = fmaf(v4, y4.x, acc.x); acc.y = fmaf(v4, y4.y, acc.y);
    acc.x = fmaf(v5, y5.x, acc.x); acc.y = fmaf(v5, y5.y, acc.y);
    acc.x = fmaf(v6, y6.x, acc.x); acc.y = fmaf(v6, y6.y, acc.y);
    acc.x = fmaf(v7, y7.x, acc.x); acc.y = fmaf(v7, y7.y, acc.y);
  }
  for (; e + 4 <= e1; e += 4){
    int2 p0 = sEdge[e+0], p1 = sEdge[e+1], p2 = sEdge[e+2], p3 = sEdge[e+3];
    float2 y0 = Y2[(size_t)p0.x*64 + lane];
    float2 y1 = Y2[(size_t)p1.x*64 + lane];
    float2 y2 = Y2[(size_t)p2.x*64 + lane];
    float2 y3 = Y2[(size_t)p3.x*64 + lane];
    float v0 = __int_as_float(p0.y), v1 = __int_as_float(p1.y);
    float v2 = __int_as_float(p2.y), v3 = __int_as_float(p3.y);
    acc.x = fmaf(v0, y0.x, acc.x); acc.y = fmaf(v0, y0.y, acc.y);
    acc.x = fmaf(v1, y1.x, acc.x); acc.y = fmaf(v1, y1.y, acc.y);
    acc.x = fmaf(v2, y2.x, acc.x); acc.y = fmaf(v2, y2.y, acc.y);
    acc.x = fmaf(v3, y3.x, acc.x); acc.y = fmaf(v3, y3.y, acc.y);
  }
  for (; e < e1; ++e){
    int2 pk = sEdge[e];
    float v = __int_as_float(pk.y);
    float2 y = Y2[(size_t)pk.x*64 + lane];
    acc.x = fmaf(v, y.x, acc.x); acc.y = fmaf(v, y.y, acc.y);
  }
  float2 o;
  o.x = (acc.x >= 0.f) ? acc.x : acc.x * SLOPE;
  o.y = (acc.y >= 0.f) ? acc.y : acc.y * SLOPE;
  ((float2*)out)[(size_t)r*64 + lane] = o;
}

// ---------------------------------------------------------------------------
extern "C" void kernel_launch(void* const* d_in, const int* in_sizes, int n_in,
                              void* d_out, int out_size, void* d_ws, size_t ws_size,
                              hipStream_t stream)
{
  const float* features = (const float*)d_in[0];
  const int*   adj_row  = (const int*)d_in[1];
  const int*   adj_col  = (const int*)d_in[2];
  const float* adj_val  = (const float*)d_in[3];
  const float* W1  = (const float*)d_in[4];
  const float* g1W = (const float*)d_in[5];
  const float* g1U = (const float*)d_in[6];
  const float* g1b = (const float*)d_in[7];
  const float* W2  = (const float*)d_in[8];
  const float* g2W = (const float*)d_in[9];
  const float* g2U = (const float*)d_in[10];
  const float* g2b = (const float*)d_in[11];

  // only timestep T-1 ever reaches the output
  const float* feat3 = features + (size_t)3*NN*KD;
  const int*   row3  = adj_row + (size_t)3*NE;
  const int*   col3  = adj_col + (size_t)3*NE;
  const float* val3  = adj_val + (size_t)3*NE;

  float* ws    = (float*)d_ws;
  float* QP    = ws;                      // ping-pong Q: [2 bufs][2 layers][16384]
  float* Tbuf  = QP + 65536;              // [2][3][16384] = 98304
  int* counts  = (int*)(Tbuf + 98304);    // 50000 (padded 50016)
  int* starts  = counts + 50016;          // 50001 (padded 50016)
  int* blockSums = starts + 50016;        // 256
  int* rank    = blockSums + 256;         // 800000
  int2* sEdge  = (int2*)(rank + NE);      // 800000 x 8B (offset 4,256,512 B: 8B-aligned)
  float* XW    = (float*)(sEdge + NE);    // 6,400,000 (25.6 MB)
  float* outF  = (float*)d_out;

  float* QA0 = QP;           float* QA1 = QP + 16384;   // buffer A (layers 0,1)
  float* QB0 = QP + 32768;   float* QB1 = QP + 49152;   // buffer B

  hipMemsetAsync(counts, 0, NN*sizeof(int), stream);
  hist_kernel<<<(NE + 1023)/1024, 256, 0, stream>>>(row3, counts, rank);
  scan1_kernel<<<SCAN_NB, 256, 0, stream>>>(counts, blockSums);
  scan3_kernel<<<SCAN_NB, 256, 0, stream>>>(counts, blockSums, starts);
  scatter_kernel<<<(NE + 1023)/1024, 256, 0, stream>>>(row3, col3, val3, rank, starts, sEdge);

  // GRU^4 on both layers' weights: iter0 reads W1/W2, then ping-pong A<->B.
  evolveA_kernel<<<24, 256, 0, stream>>>(g1W,g1U,g2W,g2U, W1,  W2,  Tbuf);
  evolveB_kernel<<< 8, 256, 0, stream>>>(g1U,g2U,g1b,g2b, Tbuf, W1,  W2,  QA0, QA1);
  evolveA_kernel<<<24, 256, 0, stream>>>(g1W,g1U,g2W,g2U, QA0, QA1, Tbuf);
  evolveB_kernel<<< 8, 256, 0, stream>>>(g1U,g2U,g1b,g2b, Tbuf, QA0, QA1, QB0, QB1);
  evolveA_kernel<<<24, 256, 0, stream>>>(g1W,g1U,g2W,g2U, QB0, QB1, Tbuf);
  evolveB_kernel<<< 8, 256, 0, stream>>>(g1U,g2U,g1b,g2b, Tbuf, QB0, QB1, QA0, QA1);
  evolveA_kernel<<<24, 256, 0, stream>>>(g1W,g1U,g2W,g2U, QA0, QA1, Tbuf);
  evolveB_kernel<<< 8, 256, 0, stream>>>(g1U,g2U,g1b,g2b, Tbuf, QA0, QA1, QB0, QB1);
  // evolved weights: W1e = QB0, W2e = QB1

  gemm_kernel<<<(NN + 127)/128, 512, 0, stream>>>(feat3, QB0, XW, NN);       // X3 @ W1e
  spmm_kernel<<<(NN + 3)/4, 256, 0, stream>>>(starts, sEdge, XW, outF);      // h1 -> d_out
  gemm_kernel<<<(NN + 127)/128, 512, 0, stream>>>(outF, QB1, XW, NN);        // h1 @ W2e
  spmm_kernel<<<(NN + 3)/4, 256, 0, stream>>>(starts, sEdge, XW, outF);      // final -> d_out
}